// Round 1
// baseline (6175.097 us; speedup 1.0000x reference)
//
#include <hip/hip_runtime.h>
#include <math.h>

#define TSEQ 2048
#define HEADS 16
#define HSZ 64
#define CDIM 1024
#define MROWS 4096   // B*T

__device__ __forceinline__ float sigf(float x) { return 1.0f / (1.0f + expf(-x)); }

// ---------------------------------------------------------------------------
// Generic f32 tiled GEMM: C[M,N] = act( A'[M,K] @ B[K,N] )
// If MIX: A'[m,k] = x[m,k] + (x[m-1,k] - x[m,k]) * mixv[k]   (x[-1] = 0 per seq)
// ACT: 0 none, 1 tanh, 2 sigmoid
// ---------------------------------------------------------------------------
template<int BM, int BN, int BK, int TM, int TN, int ACT, bool MIX>
__global__ __launch_bounds__((BM/TM)*(BN/TN))
void gemm_f32(const float* __restrict__ A, const float* __restrict__ Bm,
              float* __restrict__ C, const int M, const int N, const int K,
              const float* __restrict__ mixv)
{
    constexpr int THREADS = (BM/TM)*(BN/TN);
    __shared__ float As[BK][BM+4];
    __shared__ float Bs[BK][BN+4];
    const int tid = threadIdx.x;
    const int bm = blockIdx.y * BM;
    const int bn = blockIdx.x * BN;
    const int tx = tid % (BN/TN);
    const int ty = tid / (BN/TN);

    float acc[TM][TN];
#pragma unroll
    for (int i = 0; i < TM; ++i)
#pragma unroll
        for (int j = 0; j < TN; ++j) acc[i][j] = 0.f;

    for (int k0 = 0; k0 < K; k0 += BK) {
        // ---- A tile (BM x BK), stored k-major (transposed) into LDS ----
        for (int idx = tid*4; idx < BM*BK; idx += THREADS*4) {
            const int r  = idx / BK;
            const int kk = idx % BK;
            const int m  = bm + r;
            const float* xp = A + (size_t)m*K + (k0 + kk);
            float4 xv = *(const float4*)xp;
            if (MIX) {
                float4 xs = make_float4(0.f, 0.f, 0.f, 0.f);
                if ((m & (TSEQ-1)) != 0) xs = *(const float4*)(xp - K);
                const float4 mv = *(const float4*)(mixv + k0 + kk);
                xv.x += (xs.x - xv.x) * mv.x;
                xv.y += (xs.y - xv.y) * mv.y;
                xv.z += (xs.z - xv.z) * mv.z;
                xv.w += (xs.w - xv.w) * mv.w;
            }
            As[kk+0][r] = xv.x; As[kk+1][r] = xv.y;
            As[kk+2][r] = xv.z; As[kk+3][r] = xv.w;
        }
        // ---- B tile (BK x BN) ----
        for (int idx = tid*4; idx < BK*BN; idx += THREADS*4) {
            const int kk = idx / BN;
            const int n  = idx % BN;
            const float4 bv = *(const float4*)(Bm + (size_t)(k0+kk)*N + (bn + n));
            *(float4*)&Bs[kk][n] = bv;
        }
        __syncthreads();

#pragma unroll
        for (int kk = 0; kk < BK; ++kk) {
            float aF[TM], bF[TN];
            if constexpr ((TM & 3) == 0) {
#pragma unroll
                for (int i = 0; i < TM; i += 4)
                    *(float4*)&aF[i] = *(const float4*)&As[kk][ty*TM + i];
            } else {
#pragma unroll
                for (int i = 0; i < TM; ++i) aF[i] = As[kk][ty*TM + i];
            }
            if constexpr ((TN & 3) == 0) {
#pragma unroll
                for (int j = 0; j < TN; j += 4)
                    *(float4*)&bF[j] = *(const float4*)&Bs[kk][tx*TN + j];
            } else {
#pragma unroll
                for (int j = 0; j < TN; ++j) bF[j] = Bs[kk][tx*TN + j];
            }
#pragma unroll
            for (int i = 0; i < TM; ++i)
#pragma unroll
                for (int j = 0; j < TN; ++j)
                    acc[i][j] = fmaf(aF[i], bF[j], acc[i][j]);
        }
        __syncthreads();
    }

#pragma unroll
    for (int i = 0; i < TM; ++i) {
        const int m = bm + ty*TM + i;
#pragma unroll
        for (int j = 0; j < TN; ++j) {
            float vv = acc[i][j];
            if (ACT == 1) vv = tanhf(vv);
            else if (ACT == 2) vv = sigf(vv);
            C[(size_t)m*N + bn + tx*TN + j] = vv;
        }
    }
}

// ---------------------------------------------------------------------------
// Per-row post-processing: low-rank second GEMMs + decay + v-mix + a + l2norm
// block = one row (m), 1024 threads; wave w handles head w (64 lanes/head)
// ---------------------------------------------------------------------------
__global__ __launch_bounds__(1024)
void post_kernel(const float* __restrict__ hw, const float* __restrict__ vw,
                 const float* __restrict__ aw,
                 const float* __restrict__ w2, const float* __restrict__ v2,
                 const float* __restrict__ a2,
                 const float* __restrict__ w0, const float* __restrict__ v0p,
                 const float* __restrict__ a0p,
                 const float* __restrict__ k_k, const float* __restrict__ k_a,
                 const float* __restrict__ vfirst,
                 float* __restrict__ kio, float* __restrict__ vio,
                 float* __restrict__ dout, float* __restrict__ kkout,
                 float* __restrict__ bout)
{
    const int m = blockIdx.x;
    const int c = threadIdx.x;
    __shared__ float sh[160];                 // [0,64) hw | [64,96) vw | [96,160) aw
    if (c < 64)        sh[c] = hw[(size_t)m*64 + c];
    else if (c < 96)   sh[c] = vw[(size_t)m*32 + (c - 64)];
    else if (c < 160)  sh[c] = aw[(size_t)m*64 + (c - 96)];
    __syncthreads();

    float tw2 = 0.f, vv2 = 0.f, aa2 = 0.f;
    for (int j = 0; j < 64; ++j) tw2 = fmaf(sh[j],      w2[j*CDIM + c], tw2);
    for (int j = 0; j < 32; ++j) vv2 = fmaf(sh[64 + j], v2[j*CDIM + c], vv2);
    for (int j = 0; j < 64; ++j) aa2 = fmaf(sh[96 + j], a2[j*CDIM + c], aa2);

    const size_t o = (size_t)m*CDIM + c;
    // decay = exp(-exp(-softplus(-z)-0.5)) = exp(-e^{-1/2} * sigmoid(z))
    const float z   = w0[c] + tw2;
    const float dec = expf(-0.6065306597126334f * sigf(z));
    const float sv  = sigf(v0p[c] + vv2);
    const float vold = vio[o];
    const float vnew = vold + (vfirst[o] - vold) * sv;
    const float a    = sigf(a0p[c] + aa2);
    const float kraw = kio[o];
    const float kkr  = kraw * k_k[c];
    float ss = kkr * kkr;
#pragma unroll
    for (int mask = 1; mask < 64; mask <<= 1) ss += __shfl_xor(ss, mask);
    const float inv = fmaxf(rsqrtf(ss + 1e-12f), 1e-12f);
    const float kkv = kkr * inv;

    dout[o]  = dec;
    vio[o]   = vnew;
    kio[o]   = kraw * (1.f + (a - 1.f) * k_a[c]);
    kkout[o] = kkv;
    bout[o]  = kkv * a;
}

// ---------------------------------------------------------------------------
// Sequential scan: one block (1 wave) per (b,h); thread i owns state row i.
// S'[i][j] = S[i][j]*d[j] + sa_i*b[j] + v_i*k[j];  sa = -S@kk;  out = S'@r
// Per-t vectors are read with wave-uniform addresses (scalar-load friendly).
// ---------------------------------------------------------------------------
__global__ __launch_bounds__(64)
void scan_kernel(const float* __restrict__ r, const float* __restrict__ d,
                 const float* __restrict__ k, const float* __restrict__ v,
                 const float* __restrict__ kk, const float* __restrict__ bb,
                 float* __restrict__ y)
{
    const int bh = blockIdx.x;
    const int b  = bh >> 4;
    const int h  = bh & 15;
    const int i  = threadIdx.x;
    float S[HSZ];
#pragma unroll
    for (int j = 0; j < HSZ; ++j) S[j] = 0.f;

    size_t off = (size_t)b * TSEQ * CDIM + (size_t)h * HSZ;
    for (int t = 0; t < TSEQ; ++t, off += CDIM) {
        const float vi = v[off + i];
        float sacc = 0.f;
#pragma unroll
        for (int j = 0; j < HSZ; ++j) sacc = fmaf(S[j], kk[off + j], sacc);
        const float sa = -sacc;
        float outv = 0.f;
#pragma unroll
        for (int j = 0; j < HSZ; ++j) {
            const float Sj = fmaf(S[j], d[off + j], fmaf(sa, bb[off + j], vi * k[off + j]));
            S[j] = Sj;
            outv = fmaf(Sj, r[off + j], outv);
        }
        y[off + i] = outv;
    }
}

// ---------------------------------------------------------------------------
// GroupNorm(16 groups) + rank-1 rwkv residual + *g, in place on y.
// ---------------------------------------------------------------------------
__global__ __launch_bounds__(1024)
void gn_kernel(const float* __restrict__ r, const float* __restrict__ k,
               const float* __restrict__ v, const float* __restrict__ g,
               const float* __restrict__ rk, const float* __restrict__ gamma,
               const float* __restrict__ beta, float* __restrict__ y)
{
    const int m = blockIdx.x;
    const int c = threadIdx.x;
    const size_t o = (size_t)m*CDIM + c;
    const float yv = y[o];
    float s1 = yv, s2 = yv*yv;
#pragma unroll
    for (int mask = 1; mask < 64; mask <<= 1) {
        s1 += __shfl_xor(s1, mask);
        s2 += __shfl_xor(s2, mask);
    }
    const float mu  = s1 * (1.f/HSZ);
    const float var = s2 * (1.f/HSZ) - mu*mu;
    const float gn  = (yv - mu) * rsqrtf(var + 0.00064f) * gamma[c] + beta[c];

    float p = r[o] * k[o] * rk[c];
#pragma unroll
    for (int mask = 1; mask < 64; mask <<= 1) p += __shfl_xor(p, mask);

    y[o] = (gn + p * v[o]) * g[o];
}

// ---------------------------------------------------------------------------
extern "C" void kernel_launch(void* const* d_in, const int* in_sizes, int n_in,
                              void* d_out, int out_size, void* d_ws, size_t ws_size,
                              hipStream_t stream)
{
    const float* x      = (const float*)d_in[0];
    const float* vfirst = (const float*)d_in[1];
    const float* x_r = (const float*)d_in[2];
    const float* x_w = (const float*)d_in[3];
    const float* x_k = (const float*)d_in[4];
    const float* x_v = (const float*)d_in[5];
    const float* x_a = (const float*)d_in[6];
    const float* x_g = (const float*)d_in[7];
    const float* w0  = (const float*)d_in[8];
    const float* w1  = (const float*)d_in[9];
    const float* w2  = (const float*)d_in[10];
    const float* a0  = (const float*)d_in[11];
    const float* a1  = (const float*)d_in[12];
    const float* a2  = (const float*)d_in[13];
    const float* v0p = (const float*)d_in[14];
    const float* v1  = (const float*)d_in[15];
    const float* v2  = (const float*)d_in[16];
    const float* g1  = (const float*)d_in[17];
    const float* g2  = (const float*)d_in[18];
    const float* k_k = (const float*)d_in[19];
    const float* k_a = (const float*)d_in[20];
    const float* r_k = (const float*)d_in[21];
    const float* Wr  = (const float*)d_in[22];
    const float* Wk  = (const float*)d_in[23];
    const float* Wv  = (const float*)d_in[24];
    const float* Wo  = (const float*)d_in[25];
    const float* lng = (const float*)d_in[26];
    const float* lnb = (const float*)d_in[27];
    float* outp = (float*)d_out;

    float* ws = (float*)d_ws;
    const size_t BIG = (size_t)MROWS * CDIM;   // 4 Mi floats = 16 MB
    float* rbuf  = ws + 0*BIG;
    float* kbuf  = ws + 1*BIG;
    float* vbuf  = ws + 2*BIG;
    float* dbuf  = ws + 3*BIG;
    float* kkbuf = ws + 4*BIG;
    float* bbuf  = ws + 5*BIG;
    float* gbuf  = ws + 6*BIG;
    float* ybuf  = ws + 7*BIG;
    float* hwbuf = ws + 8*BIG;                 // 4096*64
    float* vwbuf = hwbuf + (size_t)MROWS*64;   // 4096*32
    float* awbuf = vwbuf + (size_t)MROWS*32;   // 4096*64
    float* ghbuf = awbuf + (size_t)MROWS*64;   // 4096*128

    const dim3 blk(256);
    const dim3 gBig(CDIM/128, MROWS/128);
    const dim3 gCol(1, MROWS/128);

    // big projections with fused token-shift mix
    gemm_f32<128,128,16,8,8,0,true><<<gBig, blk, 0, stream>>>(x, Wr, rbuf, MROWS, CDIM, CDIM, x_r);
    gemm_f32<128,128,16,8,8,0,true><<<gBig, blk, 0, stream>>>(x, Wk, kbuf, MROWS, CDIM, CDIM, x_k);
    gemm_f32<128,128,16,8,8,0,true><<<gBig, blk, 0, stream>>>(x, Wv, vbuf, MROWS, CDIM, CDIM, x_v);
    // low-rank first stages
    gemm_f32<128, 64,16,8,4,1,true><<<gCol, blk, 0, stream>>>(x, w1, hwbuf, MROWS,  64, CDIM, x_w);
    gemm_f32<128, 32,16,8,2,0,true><<<gCol, blk, 0, stream>>>(x, v1, vwbuf, MROWS,  32, CDIM, x_v);
    gemm_f32<128, 64,16,8,4,0,true><<<gCol, blk, 0, stream>>>(x, a1, awbuf, MROWS,  64, CDIM, x_a);
    gemm_f32<128,128,16,8,8,2,true><<<gCol, blk, 0, stream>>>(x, g1, ghbuf, MROWS, 128, CDIM, x_g);
    // g = sigmoid(xg@g1) @ g2
    gemm_f32<128,128,16,8,8,0,false><<<gBig, blk, 0, stream>>>(ghbuf, g2, gbuf, MROWS, CDIM, 128, nullptr);

    post_kernel<<<dim3(MROWS), dim3(1024), 0, stream>>>(
        hwbuf, vwbuf, awbuf, w2, v2, a2, w0, v0p, a0, k_k, k_a, vfirst,
        kbuf, vbuf, dbuf, kkbuf, bbuf);

    scan_kernel<<<dim3(32), dim3(64), 0, stream>>>(rbuf, dbuf, kbuf, vbuf, kkbuf, bbuf, ybuf);

    gn_kernel<<<dim3(MROWS), dim3(1024), 0, stream>>>(rbuf, kbuf, vbuf, gbuf, r_k, lng, lnb, ybuf);

    gemm_f32<128,128,16,8,8,0,false><<<gBig, blk, 0, stream>>>(ybuf, Wo, outp, MROWS, CDIM, CDIM, nullptr);
}

// Round 2
// 2551.793 us; speedup vs baseline: 2.4199x; 2.4199x over previous
//
#include <hip/hip_runtime.h>
#include <math.h>

#define TSEQ 2048
#define HEADS 16
#define HSZ 64
#define CDIM 1024
#define MROWS 4096   // B*T
#define CHUNK 64
#define NCHUNK (TSEQ/CHUNK)   // 32
#define NBH 32                // B*HEADS

__device__ __forceinline__ float sigf(float x) { return 1.0f / (1.0f + expf(-x)); }

// ---------------------------------------------------------------------------
// Generic f32 tiled GEMM: C[M,N] = act( A'[M,K] @ B[K,N] )
// If MIX: A'[m,k] = x[m,k] + (x[m-1,k] - x[m,k]) * mixv[k]   (x[-1] = 0 per seq)
// ACT: 0 none, 1 tanh, 2 sigmoid
// ---------------------------------------------------------------------------
template<int BM, int BN, int BK, int TM, int TN, int ACT, bool MIX>
__global__ __launch_bounds__((BM/TM)*(BN/TN))
void gemm_f32(const float* __restrict__ A, const float* __restrict__ Bm,
              float* __restrict__ C, const int M, const int N, const int K,
              const float* __restrict__ mixv)
{
    constexpr int THREADS = (BM/TM)*(BN/TN);
    __shared__ float As[BK][BM+4];
    __shared__ float Bs[BK][BN+4];
    const int tid = threadIdx.x;
    const int bm = blockIdx.y * BM;
    const int bn = blockIdx.x * BN;
    const int tx = tid % (BN/TN);
    const int ty = tid / (BN/TN);

    float acc[TM][TN];
#pragma unroll
    for (int i = 0; i < TM; ++i)
#pragma unroll
        for (int j = 0; j < TN; ++j) acc[i][j] = 0.f;

    for (int k0 = 0; k0 < K; k0 += BK) {
        for (int idx = tid*4; idx < BM*BK; idx += THREADS*4) {
            const int r  = idx / BK;
            const int kk = idx % BK;
            const int m  = bm + r;
            const float* xp = A + (size_t)m*K + (k0 + kk);
            float4 xv = *(const float4*)xp;
            if (MIX) {
                float4 xs = make_float4(0.f, 0.f, 0.f, 0.f);
                if ((m & (TSEQ-1)) != 0) xs = *(const float4*)(xp - K);
                const float4 mv = *(const float4*)(mixv + k0 + kk);
                xv.x += (xs.x - xv.x) * mv.x;
                xv.y += (xs.y - xv.y) * mv.y;
                xv.z += (xs.z - xv.z) * mv.z;
                xv.w += (xs.w - xv.w) * mv.w;
            }
            As[kk+0][r] = xv.x; As[kk+1][r] = xv.y;
            As[kk+2][r] = xv.z; As[kk+3][r] = xv.w;
        }
        for (int idx = tid*4; idx < BK*BN; idx += THREADS*4) {
            const int kk = idx / BN;
            const int n  = idx % BN;
            const float4 bv = *(const float4*)(Bm + (size_t)(k0+kk)*N + (bn + n));
            *(float4*)&Bs[kk][n] = bv;
        }
        __syncthreads();

#pragma unroll
        for (int kk = 0; kk < BK; ++kk) {
            float aF[TM], bF[TN];
            if constexpr ((TM & 3) == 0) {
#pragma unroll
                for (int i = 0; i < TM; i += 4)
                    *(float4*)&aF[i] = *(const float4*)&As[kk][ty*TM + i];
            } else {
#pragma unroll
                for (int i = 0; i < TM; ++i) aF[i] = As[kk][ty*TM + i];
            }
            if constexpr ((TN & 3) == 0) {
#pragma unroll
                for (int j = 0; j < TN; j += 4)
                    *(float4*)&bF[j] = *(const float4*)&Bs[kk][tx*TN + j];
            } else {
#pragma unroll
                for (int j = 0; j < TN; ++j) bF[j] = Bs[kk][tx*TN + j];
            }
#pragma unroll
            for (int i = 0; i < TM; ++i)
#pragma unroll
                for (int j = 0; j < TN; ++j)
                    acc[i][j] = fmaf(aF[i], bF[j], acc[i][j]);
        }
        __syncthreads();
    }

#pragma unroll
    for (int i = 0; i < TM; ++i) {
        const int m = bm + ty*TM + i;
#pragma unroll
        for (int j = 0; j < TN; ++j) {
            float vv = acc[i][j];
            if (ACT == 1) vv = tanhf(vv);
            else if (ACT == 2) vv = sigf(vv);
            C[(size_t)m*N + bn + tx*TN + j] = vv;
        }
    }
}

// ---------------------------------------------------------------------------
// Per-row post-processing (unchanged from round 1)
// ---------------------------------------------------------------------------
__global__ __launch_bounds__(1024)
void post_kernel(const float* __restrict__ hw, const float* __restrict__ vw,
                 const float* __restrict__ aw,
                 const float* __restrict__ w2, const float* __restrict__ v2,
                 const float* __restrict__ a2,
                 const float* __restrict__ w0, const float* __restrict__ v0p,
                 const float* __restrict__ a0p,
                 const float* __restrict__ k_k, const float* __restrict__ k_a,
                 const float* __restrict__ vfirst,
                 float* __restrict__ kio, float* __restrict__ vio,
                 float* __restrict__ dout, float* __restrict__ kkout,
                 float* __restrict__ bout)
{
    const int m = blockIdx.x;
    const int c = threadIdx.x;
    __shared__ float sh[160];
    if (c < 64)        sh[c] = hw[(size_t)m*64 + c];
    else if (c < 96)   sh[c] = vw[(size_t)m*32 + (c - 64)];
    else if (c < 160)  sh[c] = aw[(size_t)m*64 + (c - 96)];
    __syncthreads();

    float tw2 = 0.f, vv2 = 0.f, aa2 = 0.f;
    for (int j = 0; j < 64; ++j) tw2 = fmaf(sh[j],      w2[j*CDIM + c], tw2);
    for (int j = 0; j < 32; ++j) vv2 = fmaf(sh[64 + j], v2[j*CDIM + c], vv2);
    for (int j = 0; j < 64; ++j) aa2 = fmaf(sh[96 + j], a2[j*CDIM + c], aa2);

    const size_t o = (size_t)m*CDIM + c;
    const float z   = w0[c] + tw2;
    const float dec = expf(-0.6065306597126334f * sigf(z));
    const float sv  = sigf(v0p[c] + vv2);
    const float vold = vio[o];
    const float vnew = vold + (vfirst[o] - vold) * sv;
    const float a    = sigf(a0p[c] + aa2);
    const float kraw = kio[o];
    const float kkr  = kraw * k_k[c];
    float ss = kkr * kkr;
#pragma unroll
    for (int mask = 1; mask < 64; mask <<= 1) ss += __shfl_xor(ss, mask);
    const float inv = fmaxf(rsqrtf(ss + 1e-12f), 1e-12f);
    const float kkv = kkr * inv;

    dout[o]  = dec;
    vio[o]   = vnew;
    kio[o]   = kraw * (1.f + (a - 1.f) * k_a[c]);
    kkout[o] = kkv;
    bout[o]  = kkv * a;
}

// ---------------------------------------------------------------------------
// Scan pass 1: per (bh, chunk) compute chunk transition G (64x64) and
// offset H (64x64).  Wave 0 = G rows (init identity), wave 1 = H rows (init 0).
// Row recurrence: ga = -dot(row, kk); row = row*d + ga*bb (+ v_i*k for H).
// ---------------------------------------------------------------------------
__global__ __launch_bounds__(128)
void scan_pass1(const float* __restrict__ d, const float* __restrict__ k,
                const float* __restrict__ v, const float* __restrict__ kk,
                const float* __restrict__ bb,
                float* __restrict__ Gbuf, float* __restrict__ Hbuf)
{
    const int chunk = blockIdx.x;
    const int bh = blockIdx.y;
    const int b = bh >> 4, h = bh & 15;
    const int tid = threadIdx.x;
    const int lane = tid & 63;
    const int isH = tid >> 6;

    __shared__ float sv[4][64];   // 0=kk 1=d 2=bb 3=k

    float row[HSZ];
#pragma unroll
    for (int j = 0; j < HSZ; ++j) row[j] = 0.f;
    if (!isH) row[lane] = 1.f;    // identity init for G rows

    size_t off = ((size_t)b*TSEQ + (size_t)chunk*CHUNK) * CDIM + h*HSZ;
    for (int t = 0; t < CHUNK; ++t, off += CDIM) {
        const float vi = isH ? v[off + lane] : 0.f;
        __syncthreads();          // prev-step LDS reads done
        if (!isH) { sv[0][lane] = kk[off + lane]; sv[2][lane] = bb[off + lane]; }
        else      { sv[1][lane] = d[off + lane];  sv[3][lane] = k[off + lane]; }
        __syncthreads();

        float g0 = 0.f, g1 = 0.f, g2 = 0.f, g3 = 0.f;
#pragma unroll
        for (int j4 = 0; j4 < 16; ++j4) {
            const float4 kv = *(const float4*)&sv[0][j4*4];
            g0 = fmaf(row[j4*4+0], kv.x, g0);
            g1 = fmaf(row[j4*4+1], kv.y, g1);
            g2 = fmaf(row[j4*4+2], kv.z, g2);
            g3 = fmaf(row[j4*4+3], kv.w, g3);
        }
        const float ga = -((g0 + g1) + (g2 + g3));

        if (isH) {
#pragma unroll
            for (int j4 = 0; j4 < 16; ++j4) {
                const float4 dv = *(const float4*)&sv[1][j4*4];
                const float4 bv = *(const float4*)&sv[2][j4*4];
                const float4 kv = *(const float4*)&sv[3][j4*4];
                row[j4*4+0] = fmaf(row[j4*4+0], dv.x, fmaf(ga, bv.x, vi * kv.x));
                row[j4*4+1] = fmaf(row[j4*4+1], dv.y, fmaf(ga, bv.y, vi * kv.y));
                row[j4*4+2] = fmaf(row[j4*4+2], dv.z, fmaf(ga, bv.z, vi * kv.z));
                row[j4*4+3] = fmaf(row[j4*4+3], dv.w, fmaf(ga, bv.w, vi * kv.w));
            }
        } else {
#pragma unroll
            for (int j4 = 0; j4 < 16; ++j4) {
                const float4 dv = *(const float4*)&sv[1][j4*4];
                const float4 bv = *(const float4*)&sv[2][j4*4];
                row[j4*4+0] = fmaf(row[j4*4+0], dv.x, ga * bv.x);
                row[j4*4+1] = fmaf(row[j4*4+1], dv.y, ga * bv.y);
                row[j4*4+2] = fmaf(row[j4*4+2], dv.z, ga * bv.z);
                row[j4*4+3] = fmaf(row[j4*4+3], dv.w, ga * bv.w);
            }
        }
    }

    float* dst = (isH ? Hbuf : Gbuf) + (((size_t)bh*NCHUNK + chunk)*HSZ + lane)*HSZ;
#pragma unroll
    for (int j4 = 0; j4 < 16; ++j4)
        *(float4*)&dst[j4*4] = make_float4(row[j4*4+0], row[j4*4+1], row[j4*4+2], row[j4*4+3]);
}

// ---------------------------------------------------------------------------
// Scan pass 2: propagate chunk-boundary states.  S0[c] stored (state entering
// chunk c), then S = S @ G_c + H_c.  Rows are independent -> grid (4 rowgrp,
// 32 bh), 256 threads = 16 rows x 16 col-quads per block.
// ---------------------------------------------------------------------------
__global__ __launch_bounds__(256)
void scan_pass2(const float* __restrict__ Gbuf, const float* __restrict__ Hbuf,
                float* __restrict__ S0buf)
{
    const int rg = blockIdx.x;        // row group 0..3 (16 rows each)
    const int bh = blockIdx.y;
    const int tid = threadIdx.x;
    const int il = tid & 15;          // local row
    const int q4 = tid >> 4;          // col quad 0..15
    const int row = rg*16 + il;

    __shared__ float Gs[64][68];
    __shared__ float Ssh[16][68];

    float frag[4] = {0.f, 0.f, 0.f, 0.f};
    *(float4*)&Ssh[il][q4*4] = make_float4(0.f, 0.f, 0.f, 0.f);

    for (int c = 0; c < NCHUNK; ++c) {
        const size_t mbase = ((size_t)bh*NCHUNK + c)*HSZ*HSZ;
        // stage G
#pragma unroll
        for (int p = 0; p < 4; ++p) {
            const int f = tid*16 + p*4;
            const int rr = f >> 6, cc = f & 63;
            *(float4*)&Gs[rr][cc] = *(const float4*)(Gbuf + mbase + f);
        }
        // store S0 (state entering chunk c)
        *(float4*)(S0buf + mbase + (size_t)row*HSZ + q4*4) =
            make_float4(frag[0], frag[1], frag[2], frag[3]);
        __syncthreads();   // Gs + Ssh ready

        float4 hv = *(const float4*)(Hbuf + mbase + (size_t)row*HSZ + q4*4);
        float a0 = hv.x, a1 = hv.y, a2 = hv.z, a3 = hv.w;
#pragma unroll
        for (int j = 0; j < 64; ++j) {
            const float sj = Ssh[il][j];
            const float4 gv = *(const float4*)&Gs[j][q4*4];
            a0 = fmaf(sj, gv.x, a0);
            a1 = fmaf(sj, gv.y, a1);
            a2 = fmaf(sj, gv.z, a2);
            a3 = fmaf(sj, gv.w, a3);
        }
        __syncthreads();   // all reads of Ssh/Gs done
        frag[0] = a0; frag[1] = a1; frag[2] = a2; frag[3] = a3;
        *(float4*)&Ssh[il][q4*4] = make_float4(a0, a1, a2, a3);
    }
}

// ---------------------------------------------------------------------------
// Scan pass 3: replay each chunk from its known S0, producing y.
// One wave per (bh, chunk); thread i owns state row i.
// ---------------------------------------------------------------------------
__global__ __launch_bounds__(64)
void scan_pass3(const float* __restrict__ r, const float* __restrict__ d,
                const float* __restrict__ k, const float* __restrict__ v,
                const float* __restrict__ kk, const float* __restrict__ bb,
                const float* __restrict__ S0buf, float* __restrict__ y)
{
    const int chunk = blockIdx.x;
    const int bh = blockIdx.y;
    const int b = bh >> 4, h = bh & 15;
    const int i = threadIdx.x;

    __shared__ float sv[5][64];   // 0=kk 1=d 2=bb 3=k 4=r

    float S[HSZ];
    const float* s0p = S0buf + (((size_t)bh*NCHUNK + chunk)*HSZ + i)*HSZ;
#pragma unroll
    for (int j4 = 0; j4 < 16; ++j4) {
        const float4 s4 = *(const float4*)&s0p[j4*4];
        S[j4*4+0] = s4.x; S[j4*4+1] = s4.y; S[j4*4+2] = s4.z; S[j4*4+3] = s4.w;
    }

    size_t off = ((size_t)b*TSEQ + (size_t)chunk*CHUNK) * CDIM + h*HSZ;
    for (int t = 0; t < CHUNK; ++t, off += CDIM) {
        const float vi = v[off + i];
        __syncthreads();
        sv[0][i] = kk[off + i];
        sv[1][i] = d[off + i];
        sv[2][i] = bb[off + i];
        sv[3][i] = k[off + i];
        sv[4][i] = r[off + i];
        __syncthreads();

        float g0 = 0.f, g1 = 0.f, g2 = 0.f, g3 = 0.f;
#pragma unroll
        for (int j4 = 0; j4 < 16; ++j4) {
            const float4 kv = *(const float4*)&sv[0][j4*4];
            g0 = fmaf(S[j4*4+0], kv.x, g0);
            g1 = fmaf(S[j4*4+1], kv.y, g1);
            g2 = fmaf(S[j4*4+2], kv.z, g2);
            g3 = fmaf(S[j4*4+3], kv.w, g3);
        }
        const float sa = -((g0 + g1) + (g2 + g3));

        float o0 = 0.f, o1 = 0.f, o2 = 0.f, o3 = 0.f;
#pragma unroll
        for (int j4 = 0; j4 < 16; ++j4) {
            const float4 dv = *(const float4*)&sv[1][j4*4];
            const float4 bv = *(const float4*)&sv[2][j4*4];
            const float4 kv = *(const float4*)&sv[3][j4*4];
            const float4 rv = *(const float4*)&sv[4][j4*4];
            const float s0n = fmaf(S[j4*4+0], dv.x, fmaf(sa, bv.x, vi * kv.x));
            const float s1n = fmaf(S[j4*4+1], dv.y, fmaf(sa, bv.y, vi * kv.y));
            const float s2n = fmaf(S[j4*4+2], dv.z, fmaf(sa, bv.z, vi * kv.z));
            const float s3n = fmaf(S[j4*4+3], dv.w, fmaf(sa, bv.w, vi * kv.w));
            S[j4*4+0] = s0n; S[j4*4+1] = s1n; S[j4*4+2] = s2n; S[j4*4+3] = s3n;
            o0 = fmaf(s0n, rv.x, o0);
            o1 = fmaf(s1n, rv.y, o1);
            o2 = fmaf(s2n, rv.z, o2);
            o3 = fmaf(s3n, rv.w, o3);
        }
        y[off + i] = (o0 + o1) + (o2 + o3);
    }
}

// ---------------------------------------------------------------------------
// GroupNorm(16 groups) + rank-1 rwkv residual + *g, in place on y.
// ---------------------------------------------------------------------------
__global__ __launch_bounds__(1024)
void gn_kernel(const float* __restrict__ r, const float* __restrict__ k,
               const float* __restrict__ v, const float* __restrict__ g,
               const float* __restrict__ rk, const float* __restrict__ gamma,
               const float* __restrict__ beta, float* __restrict__ y)
{
    const int m = blockIdx.x;
    const int c = threadIdx.x;
    const size_t o = (size_t)m*CDIM + c;
    const float yv = y[o];
    float s1 = yv, s2 = yv*yv;
#pragma unroll
    for (int mask = 1; mask < 64; mask <<= 1) {
        s1 += __shfl_xor(s1, mask);
        s2 += __shfl_xor(s2, mask);
    }
    const float mu  = s1 * (1.f/HSZ);
    const float var = s2 * (1.f/HSZ) - mu*mu;
    const float gn  = (yv - mu) * rsqrtf(var + 0.00064f) * gamma[c] + beta[c];

    float p = r[o] * k[o] * rk[c];
#pragma unroll
    for (int mask = 1; mask < 64; mask <<= 1) p += __shfl_xor(p, mask);

    y[o] = (gn + p * v[o]) * g[o];
}

// ---------------------------------------------------------------------------
extern "C" void kernel_launch(void* const* d_in, const int* in_sizes, int n_in,
                              void* d_out, int out_size, void* d_ws, size_t ws_size,
                              hipStream_t stream)
{
    const float* x      = (const float*)d_in[0];
    const float* vfirst = (const float*)d_in[1];
    const float* x_r = (const float*)d_in[2];
    const float* x_w = (const float*)d_in[3];
    const float* x_k = (const float*)d_in[4];
    const float* x_v = (const float*)d_in[5];
    const float* x_a = (const float*)d_in[6];
    const float* x_g = (const float*)d_in[7];
    const float* w0  = (const float*)d_in[8];
    const float* w1  = (const float*)d_in[9];
    const float* w2  = (const float*)d_in[10];
    const float* a0  = (const float*)d_in[11];
    const float* a1  = (const float*)d_in[12];
    const float* a2  = (const float*)d_in[13];
    const float* v0p = (const float*)d_in[14];
    const float* v1  = (const float*)d_in[15];
    const float* v2  = (const float*)d_in[16];
    const float* g1  = (const float*)d_in[17];
    const float* g2  = (const float*)d_in[18];
    const float* k_k = (const float*)d_in[19];
    const float* k_a = (const float*)d_in[20];
    const float* r_k = (const float*)d_in[21];
    const float* Wr  = (const float*)d_in[22];
    const float* Wk  = (const float*)d_in[23];
    const float* Wv  = (const float*)d_in[24];
    const float* Wo  = (const float*)d_in[25];
    const float* lng = (const float*)d_in[26];
    const float* lnb = (const float*)d_in[27];
    float* outp = (float*)d_out;

    float* ws = (float*)d_ws;
    const size_t BIG = (size_t)MROWS * CDIM;   // 4 Mi floats = 16 MB
    float* rbuf  = ws + 0*BIG;
    float* kbuf  = ws + 1*BIG;
    float* vbuf  = ws + 2*BIG;
    float* dbuf  = ws + 3*BIG;
    float* kkbuf = ws + 4*BIG;
    float* bbuf  = ws + 5*BIG;
    float* gbuf  = ws + 6*BIG;   // doubles as Hbuf before g-GEMM
    float* ybuf  = ws + 7*BIG;   // doubles as Gbuf before pass3
    float* hwbuf = ws + 8*BIG;
    float* vwbuf = hwbuf + (size_t)MROWS*64;
    float* awbuf = vwbuf + (size_t)MROWS*32;
    float* ghbuf = awbuf + (size_t)MROWS*64;

    float* Gbuf  = ybuf;
    float* Hbuf  = gbuf;
    float* S0buf = outp;         // d_out as scratch; overwritten by final GEMM

    const dim3 blk(256);
    const dim3 gBig(CDIM/128, MROWS/128);
    const dim3 gCol(1, MROWS/128);

    // big projections with fused token-shift mix
    gemm_f32<128,128,16,8,8,0,true><<<gBig, blk, 0, stream>>>(x, Wr, rbuf, MROWS, CDIM, CDIM, x_r);
    gemm_f32<128,128,16,8,8,0,true><<<gBig, blk, 0, stream>>>(x, Wk, kbuf, MROWS, CDIM, CDIM, x_k);
    gemm_f32<128,128,16,8,8,0,true><<<gBig, blk, 0, stream>>>(x, Wv, vbuf, MROWS, CDIM, CDIM, x_v);
    // low-rank first stages
    gemm_f32<128, 64,16,8,4,1,true><<<gCol, blk, 0, stream>>>(x, w1, hwbuf, MROWS,  64, CDIM, x_w);
    gemm_f32<128, 32,16,8,2,0,true><<<gCol, blk, 0, stream>>>(x, v1, vwbuf, MROWS,  32, CDIM, x_v);
    gemm_f32<128, 64,16,8,4,0,true><<<gCol, blk, 0, stream>>>(x, a1, awbuf, MROWS,  64, CDIM, x_a);

    post_kernel<<<dim3(MROWS), dim3(1024), 0, stream>>>(
        hwbuf, vwbuf, awbuf, w2, v2, a2, w0, v0p, a0, k_k, k_a, vfirst,
        kbuf, vbuf, dbuf, kkbuf, bbuf);

    // chunked scan
    scan_pass1<<<dim3(NCHUNK, NBH), dim3(128), 0, stream>>>(
        dbuf, kbuf, vbuf, kkbuf, bbuf, Gbuf, Hbuf);
    scan_pass2<<<dim3(4, NBH), dim3(256), 0, stream>>>(Gbuf, Hbuf, S0buf);
    scan_pass3<<<dim3(NCHUNK, NBH), dim3(64), 0, stream>>>(
        rbuf, dbuf, kbuf, vbuf, kkbuf, bbuf, S0buf, ybuf);

    // g gate (after scan so gbuf could serve as Hbuf)
    gemm_f32<128,128,16,8,8,2,true><<<gCol, blk, 0, stream>>>(x, g1, ghbuf, MROWS, 128, CDIM, x_g);
    gemm_f32<128,128,16,8,8,0,false><<<gBig, blk, 0, stream>>>(ghbuf, g2, gbuf, MROWS, CDIM, 128, nullptr);

    gn_kernel<<<dim3(MROWS), dim3(1024), 0, stream>>>(rbuf, kbuf, vbuf, gbuf, r_k, lng, lnb, ybuf);

    gemm_f32<128,128,16,8,8,0,false><<<gBig, blk, 0, stream>>>(ybuf, Wo, outp, MROWS, CDIM, CDIM, nullptr);
}

// Round 3
// 1830.212 us; speedup vs baseline: 3.3740x; 1.3943x over previous
//
#include <hip/hip_runtime.h>
#include <math.h>

#define TSEQ 2048
#define HEADS 16
#define HSZ 64
#define CDIM 1024
#define MROWS 4096   // B*T
#define CHUNK 64
#define NCHUNK (TSEQ/CHUNK)   // 32
#define NBH 32                // B*HEADS

__device__ __forceinline__ float sigf(float x) { return 1.0f / (1.0f + expf(-x)); }

// ---------------------------------------------------------------------------
// Generic f32 tiled GEMM: C[M,N] = act( A'[M,K] @ B[K,N] )
// If MIX: A'[m,k] = x[m,k] + (x[m-1,k] - x[m,k]) * mixv[k]   (x[-1] = 0 per seq)
// ACT: 0 none, 1 tanh, 2 sigmoid
// ---------------------------------------------------------------------------
template<int BM, int BN, int BK, int TM, int TN, int ACT, bool MIX>
__global__ __launch_bounds__((BM/TM)*(BN/TN))
void gemm_f32(const float* __restrict__ A, const float* __restrict__ Bm,
              float* __restrict__ C, const int M, const int N, const int K,
              const float* __restrict__ mixv)
{
    constexpr int THREADS = (BM/TM)*(BN/TN);
    __shared__ float As[BK][BM+4];
    __shared__ float Bs[BK][BN+4];
    const int tid = threadIdx.x;
    const int bm = blockIdx.y * BM;
    const int bn = blockIdx.x * BN;
    const int tx = tid % (BN/TN);
    const int ty = tid / (BN/TN);

    float acc[TM][TN];
#pragma unroll
    for (int i = 0; i < TM; ++i)
#pragma unroll
        for (int j = 0; j < TN; ++j) acc[i][j] = 0.f;

    for (int k0 = 0; k0 < K; k0 += BK) {
        for (int idx = tid*4; idx < BM*BK; idx += THREADS*4) {
            const int r  = idx / BK;
            const int kk = idx % BK;
            const int m  = bm + r;
            const float* xp = A + (size_t)m*K + (k0 + kk);
            float4 xv = *(const float4*)xp;
            if (MIX) {
                float4 xs = make_float4(0.f, 0.f, 0.f, 0.f);
                if ((m & (TSEQ-1)) != 0) xs = *(const float4*)(xp - K);
                const float4 mv = *(const float4*)(mixv + k0 + kk);
                xv.x += (xs.x - xv.x) * mv.x;
                xv.y += (xs.y - xv.y) * mv.y;
                xv.z += (xs.z - xv.z) * mv.z;
                xv.w += (xs.w - xv.w) * mv.w;
            }
            As[kk+0][r] = xv.x; As[kk+1][r] = xv.y;
            As[kk+2][r] = xv.z; As[kk+3][r] = xv.w;
        }
        for (int idx = tid*4; idx < BK*BN; idx += THREADS*4) {
            const int kk = idx / BN;
            const int n  = idx % BN;
            const float4 bv = *(const float4*)(Bm + (size_t)(k0+kk)*N + (bn + n));
            *(float4*)&Bs[kk][n] = bv;
        }
        __syncthreads();

#pragma unroll
        for (int kk = 0; kk < BK; ++kk) {
            float aF[TM], bF[TN];
            if constexpr ((TM & 3) == 0) {
#pragma unroll
                for (int i = 0; i < TM; i += 4)
                    *(float4*)&aF[i] = *(const float4*)&As[kk][ty*TM + i];
            } else {
#pragma unroll
                for (int i = 0; i < TM; ++i) aF[i] = As[kk][ty*TM + i];
            }
            if constexpr ((TN & 3) == 0) {
#pragma unroll
                for (int j = 0; j < TN; j += 4)
                    *(float4*)&bF[j] = *(const float4*)&Bs[kk][tx*TN + j];
            } else {
#pragma unroll
                for (int j = 0; j < TN; ++j) bF[j] = Bs[kk][tx*TN + j];
            }
#pragma unroll
            for (int i = 0; i < TM; ++i)
#pragma unroll
                for (int j = 0; j < TN; ++j)
                    acc[i][j] = fmaf(aF[i], bF[j], acc[i][j]);
        }
        __syncthreads();
    }

#pragma unroll
    for (int i = 0; i < TM; ++i) {
        const int m = bm + ty*TM + i;
#pragma unroll
        for (int j = 0; j < TN; ++j) {
            float vv = acc[i][j];
            if (ACT == 1) vv = tanhf(vv);
            else if (ACT == 2) vv = sigf(vv);
            C[(size_t)m*N + bn + tx*TN + j] = vv;
        }
    }
}

// ---------------------------------------------------------------------------
// Per-row post-processing
// ---------------------------------------------------------------------------
__global__ __launch_bounds__(1024)
void post_kernel(const float* __restrict__ hw, const float* __restrict__ vw,
                 const float* __restrict__ aw,
                 const float* __restrict__ w2, const float* __restrict__ v2,
                 const float* __restrict__ a2,
                 const float* __restrict__ w0, const float* __restrict__ v0p,
                 const float* __restrict__ a0p,
                 const float* __restrict__ k_k, const float* __restrict__ k_a,
                 const float* __restrict__ vfirst,
                 float* __restrict__ kio, float* __restrict__ vio,
                 float* __restrict__ dout, float* __restrict__ kkout,
                 float* __restrict__ bout)
{
    const int m = blockIdx.x;
    const int c = threadIdx.x;
    __shared__ float sh[160];
    if (c < 64)        sh[c] = hw[(size_t)m*64 + c];
    else if (c < 96)   sh[c] = vw[(size_t)m*32 + (c - 64)];
    else if (c < 160)  sh[c] = aw[(size_t)m*64 + (c - 96)];
    __syncthreads();

    float tw2 = 0.f, vv2 = 0.f, aa2 = 0.f;
    for (int j = 0; j < 64; ++j) tw2 = fmaf(sh[j],      w2[j*CDIM + c], tw2);
    for (int j = 0; j < 32; ++j) vv2 = fmaf(sh[64 + j], v2[j*CDIM + c], vv2);
    for (int j = 0; j < 64; ++j) aa2 = fmaf(sh[96 + j], a2[j*CDIM + c], aa2);

    const size_t o = (size_t)m*CDIM + c;
    const float z   = w0[c] + tw2;
    const float dec = expf(-0.6065306597126334f * sigf(z));
    const float sv  = sigf(v0p[c] + vv2);
    const float vold = vio[o];
    const float vnew = vold + (vfirst[o] - vold) * sv;
    const float a    = sigf(a0p[c] + aa2);
    const float kraw = kio[o];
    const float kkr  = kraw * k_k[c];
    float ss = kkr * kkr;
#pragma unroll
    for (int mask = 1; mask < 64; mask <<= 1) ss += __shfl_xor(ss, mask);
    const float inv = fmaxf(rsqrtf(ss + 1e-12f), 1e-12f);
    const float kkv = kkr * inv;

    dout[o]  = dec;
    vio[o]   = vnew;
    kio[o]   = kraw * (1.f + (a - 1.f) * k_a[c]);
    kkout[o] = kkv;
    bout[o]  = kkv * a;
}

// ---------------------------------------------------------------------------
// Scan pass 1: per (bh, chunk) compute chunk transition G (64x64) and
// offset H (64x64).  Wave 0 = G rows (init identity), wave 1 = H rows (init 0).
// NOTE: row[] must only ever be indexed with compile-time constants — a
// runtime index (row[lane]) sends the whole array to scratch (rule #20;
// round-2 postmortem: VGPR=32, 2.2 GB scratch writes, 820 us).
// ---------------------------------------------------------------------------
__global__ __launch_bounds__(128)
void scan_pass1(const float* __restrict__ d, const float* __restrict__ k,
                const float* __restrict__ v, const float* __restrict__ kk,
                const float* __restrict__ bb,
                float* __restrict__ Gbuf, float* __restrict__ Hbuf)
{
    const int chunk = blockIdx.x;
    const int bh = blockIdx.y;
    const int b = bh >> 4, h = bh & 15;
    const int tid = threadIdx.x;
    const int lane = tid & 63;
    const int isH = tid >> 6;

    __shared__ float sv[4][64];   // 0=kk 1=d 2=bb 3=k

    float row[HSZ];
#pragma unroll
    for (int j = 0; j < HSZ; ++j)
        row[j] = (!isH && j == lane) ? 1.f : 0.f;   // identity for G, 0 for H

    size_t off = ((size_t)b*TSEQ + (size_t)chunk*CHUNK) * CDIM + h*HSZ;
    for (int t = 0; t < CHUNK; ++t, off += CDIM) {
        const float vi = isH ? v[off + lane] : 0.f;
        __syncthreads();          // prev-step LDS reads done
        if (!isH) { sv[0][lane] = kk[off + lane]; sv[2][lane] = bb[off + lane]; }
        else      { sv[1][lane] = d[off + lane];  sv[3][lane] = k[off + lane]; }
        __syncthreads();

        float g0 = 0.f, g1 = 0.f, g2 = 0.f, g3 = 0.f;
#pragma unroll
        for (int j4 = 0; j4 < 16; ++j4) {
            const float4 kv = *(const float4*)&sv[0][j4*4];
            g0 = fmaf(row[j4*4+0], kv.x, g0);
            g1 = fmaf(row[j4*4+1], kv.y, g1);
            g2 = fmaf(row[j4*4+2], kv.z, g2);
            g3 = fmaf(row[j4*4+3], kv.w, g3);
        }
        const float ga = -((g0 + g1) + (g2 + g3));

        if (isH) {
#pragma unroll
            for (int j4 = 0; j4 < 16; ++j4) {
                const float4 dv = *(const float4*)&sv[1][j4*4];
                const float4 bv = *(const float4*)&sv[2][j4*4];
                const float4 kv = *(const float4*)&sv[3][j4*4];
                row[j4*4+0] = fmaf(row[j4*4+0], dv.x, fmaf(ga, bv.x, vi * kv.x));
                row[j4*4+1] = fmaf(row[j4*4+1], dv.y, fmaf(ga, bv.y, vi * kv.y));
                row[j4*4+2] = fmaf(row[j4*4+2], dv.z, fmaf(ga, bv.z, vi * kv.z));
                row[j4*4+3] = fmaf(row[j4*4+3], dv.w, fmaf(ga, bv.w, vi * kv.w));
            }
        } else {
#pragma unroll
            for (int j4 = 0; j4 < 16; ++j4) {
                const float4 dv = *(const float4*)&sv[1][j4*4];
                const float4 bv = *(const float4*)&sv[2][j4*4];
                row[j4*4+0] = fmaf(row[j4*4+0], dv.x, ga * bv.x);
                row[j4*4+1] = fmaf(row[j4*4+1], dv.y, ga * bv.y);
                row[j4*4+2] = fmaf(row[j4*4+2], dv.z, ga * bv.z);
                row[j4*4+3] = fmaf(row[j4*4+3], dv.w, ga * bv.w);
            }
        }
    }

    float* dst = (isH ? Hbuf : Gbuf) + (((size_t)bh*NCHUNK + chunk)*HSZ + lane)*HSZ;
#pragma unroll
    for (int j4 = 0; j4 < 16; ++j4)
        *(float4*)&dst[j4*4] = make_float4(row[j4*4+0], row[j4*4+1], row[j4*4+2], row[j4*4+3]);
}

// ---------------------------------------------------------------------------
// Scan pass 2: propagate chunk-boundary states.  S0[c] stored (state entering
// chunk c), then S = S @ G_c + H_c.
// ---------------------------------------------------------------------------
__global__ __launch_bounds__(256)
void scan_pass2(const float* __restrict__ Gbuf, const float* __restrict__ Hbuf,
                float* __restrict__ S0buf)
{
    const int rg = blockIdx.x;        // row group 0..3 (16 rows each)
    const int bh = blockIdx.y;
    const int tid = threadIdx.x;
    const int il = tid & 15;          // local row
    const int q4 = tid >> 4;          // col quad 0..15
    const int row = rg*16 + il;

    __shared__ float Gs[64][68];
    __shared__ float Ssh[16][68];

    float frag[4] = {0.f, 0.f, 0.f, 0.f};
    *(float4*)&Ssh[il][q4*4] = make_float4(0.f, 0.f, 0.f, 0.f);

    for (int c = 0; c < NCHUNK; ++c) {
        const size_t mbase = ((size_t)bh*NCHUNK + c)*HSZ*HSZ;
#pragma unroll
        for (int p = 0; p < 4; ++p) {
            const int f = tid*16 + p*4;
            const int rr = f >> 6, cc = f & 63;
            *(float4*)&Gs[rr][cc] = *(const float4*)(Gbuf + mbase + f);
        }
        *(float4*)(S0buf + mbase + (size_t)row*HSZ + q4*4) =
            make_float4(frag[0], frag[1], frag[2], frag[3]);
        __syncthreads();   // Gs + Ssh ready

        float4 hv = *(const float4*)(Hbuf + mbase + (size_t)row*HSZ + q4*4);
        float a0 = hv.x, a1 = hv.y, a2 = hv.z, a3 = hv.w;
#pragma unroll
        for (int j = 0; j < 64; ++j) {
            const float sj = Ssh[il][j];
            const float4 gv = *(const float4*)&Gs[j][q4*4];
            a0 = fmaf(sj, gv.x, a0);
            a1 = fmaf(sj, gv.y, a1);
            a2 = fmaf(sj, gv.z, a2);
            a3 = fmaf(sj, gv.w, a3);
        }
        __syncthreads();   // all reads of Ssh/Gs done
        frag[0] = a0; frag[1] = a1; frag[2] = a2; frag[3] = a3;
        *(float4*)&Ssh[il][q4*4] = make_float4(a0, a1, a2, a3);
    }
}

// ---------------------------------------------------------------------------
// Scan pass 3: replay each chunk from its known S0, producing y.
// ---------------------------------------------------------------------------
__global__ __launch_bounds__(64)
void scan_pass3(const float* __restrict__ r, const float* __restrict__ d,
                const float* __restrict__ k, const float* __restrict__ v,
                const float* __restrict__ kk, const float* __restrict__ bb,
                const float* __restrict__ S0buf, float* __restrict__ y)
{
    const int chunk = blockIdx.x;
    const int bh = blockIdx.y;
    const int b = bh >> 4, h = bh & 15;
    const int i = threadIdx.x;

    __shared__ float sv[5][64];   // 0=kk 1=d 2=bb 3=k 4=r

    float S[HSZ];
    const float* s0p = S0buf + (((size_t)bh*NCHUNK + chunk)*HSZ + i)*HSZ;
#pragma unroll
    for (int j4 = 0; j4 < 16; ++j4) {
        const float4 s4 = *(const float4*)&s0p[j4*4];
        S[j4*4+0] = s4.x; S[j4*4+1] = s4.y; S[j4*4+2] = s4.z; S[j4*4+3] = s4.w;
    }

    size_t off = ((size_t)b*TSEQ + (size_t)chunk*CHUNK) * CDIM + h*HSZ;
    for (int t = 0; t < CHUNK; ++t, off += CDIM) {
        const float vi = v[off + i];
        __syncthreads();
        sv[0][i] = kk[off + i];
        sv[1][i] = d[off + i];
        sv[2][i] = bb[off + i];
        sv[3][i] = k[off + i];
        sv[4][i] = r[off + i];
        __syncthreads();

        float g0 = 0.f, g1 = 0.f, g2 = 0.f, g3 = 0.f;
#pragma unroll
        for (int j4 = 0; j4 < 16; ++j4) {
            const float4 kv = *(const float4*)&sv[0][j4*4];
            g0 = fmaf(S[j4*4+0], kv.x, g0);
            g1 = fmaf(S[j4*4+1], kv.y, g1);
            g2 = fmaf(S[j4*4+2], kv.z, g2);
            g3 = fmaf(S[j4*4+3], kv.w, g3);
        }
        const float sa = -((g0 + g1) + (g2 + g3));

        float o0 = 0.f, o1 = 0.f, o2 = 0.f, o3 = 0.f;
#pragma unroll
        for (int j4 = 0; j4 < 16; ++j4) {
            const float4 dv = *(const float4*)&sv[1][j4*4];
            const float4 bv = *(const float4*)&sv[2][j4*4];
            const float4 kv = *(const float4*)&sv[3][j4*4];
            const float4 rv = *(const float4*)&sv[4][j4*4];
            const float s0n = fmaf(S[j4*4+0], dv.x, fmaf(sa, bv.x, vi * kv.x));
            const float s1n = fmaf(S[j4*4+1], dv.y, fmaf(sa, bv.y, vi * kv.y));
            const float s2n = fmaf(S[j4*4+2], dv.z, fmaf(sa, bv.z, vi * kv.z));
            const float s3n = fmaf(S[j4*4+3], dv.w, fmaf(sa, bv.w, vi * kv.w));
            S[j4*4+0] = s0n; S[j4*4+1] = s1n; S[j4*4+2] = s2n; S[j4*4+3] = s3n;
            o0 = fmaf(s0n, rv.x, o0);
            o1 = fmaf(s1n, rv.y, o1);
            o2 = fmaf(s2n, rv.z, o2);
            o3 = fmaf(s3n, rv.w, o3);
        }
        y[off + i] = (o0 + o1) + (o2 + o3);
    }
}

// ---------------------------------------------------------------------------
// GroupNorm(16 groups) + rank-1 rwkv residual + *g, in place on y.
// ---------------------------------------------------------------------------
__global__ __launch_bounds__(1024)
void gn_kernel(const float* __restrict__ r, const float* __restrict__ k,
               const float* __restrict__ v, const float* __restrict__ g,
               const float* __restrict__ rk, const float* __restrict__ gamma,
               const float* __restrict__ beta, float* __restrict__ y)
{
    const int m = blockIdx.x;
    const int c = threadIdx.x;
    const size_t o = (size_t)m*CDIM + c;
    const float yv = y[o];
    float s1 = yv, s2 = yv*yv;
#pragma unroll
    for (int mask = 1; mask < 64; mask <<= 1) {
        s1 += __shfl_xor(s1, mask);
        s2 += __shfl_xor(s2, mask);
    }
    const float mu  = s1 * (1.f/HSZ);
    const float var = s2 * (1.f/HSZ) - mu*mu;
    const float gn  = (yv - mu) * rsqrtf(var + 0.00064f) * gamma[c] + beta[c];

    float p = r[o] * k[o] * rk[c];
#pragma unroll
    for (int mask = 1; mask < 64; mask <<= 1) p += __shfl_xor(p, mask);

    y[o] = (gn + p * v[o]) * g[o];
}

// ---------------------------------------------------------------------------
extern "C" void kernel_launch(void* const* d_in, const int* in_sizes, int n_in,
                              void* d_out, int out_size, void* d_ws, size_t ws_size,
                              hipStream_t stream)
{
    const float* x      = (const float*)d_in[0];
    const float* vfirst = (const float*)d_in[1];
    const float* x_r = (const float*)d_in[2];
    const float* x_w = (const float*)d_in[3];
    const float* x_k = (const float*)d_in[4];
    const float* x_v = (const float*)d_in[5];
    const float* x_a = (const float*)d_in[6];
    const float* x_g = (const float*)d_in[7];
    const float* w0  = (const float*)d_in[8];
    const float* w1  = (const float*)d_in[9];
    const float* w2  = (const float*)d_in[10];
    const float* a0  = (const float*)d_in[11];
    const float* a1  = (const float*)d_in[12];
    const float* a2  = (const float*)d_in[13];
    const float* v0p = (const float*)d_in[14];
    const float* v1  = (const float*)d_in[15];
    const float* v2  = (const float*)d_in[16];
    const float* g1  = (const float*)d_in[17];
    const float* g2  = (const float*)d_in[18];
    const float* k_k = (const float*)d_in[19];
    const float* k_a = (const float*)d_in[20];
    const float* r_k = (const float*)d_in[21];
    const float* Wr  = (const float*)d_in[22];
    const float* Wk  = (const float*)d_in[23];
    const float* Wv  = (const float*)d_in[24];
    const float* Wo  = (const float*)d_in[25];
    const float* lng = (const float*)d_in[26];
    const float* lnb = (const float*)d_in[27];
    float* outp = (float*)d_out;

    float* ws = (float*)d_ws;
    const size_t BIG = (size_t)MROWS * CDIM;   // 4 Mi floats = 16 MB
    float* rbuf  = ws + 0*BIG;
    float* kbuf  = ws + 1*BIG;
    float* vbuf  = ws + 2*BIG;
    float* dbuf  = ws + 3*BIG;
    float* kkbuf = ws + 4*BIG;
    float* bbuf  = ws + 5*BIG;
    float* gbuf  = ws + 6*BIG;   // doubles as Hbuf before g-GEMM
    float* ybuf  = ws + 7*BIG;   // doubles as Gbuf before pass3
    float* hwbuf = ws + 8*BIG;
    float* vwbuf = hwbuf + (size_t)MROWS*64;
    float* awbuf = vwbuf + (size_t)MROWS*32;
    float* ghbuf = awbuf + (size_t)MROWS*64;

    float* Gbuf  = ybuf;
    float* Hbuf  = gbuf;
    float* S0buf = outp;         // d_out as scratch; overwritten by final GEMM

    const dim3 blk(256);
    const dim3 gBig(CDIM/128, MROWS/128);
    const dim3 gCol(1, MROWS/128);

    // big projections with fused token-shift mix
    gemm_f32<128,128,16,8,8,0,true><<<gBig, blk, 0, stream>>>(x, Wr, rbuf, MROWS, CDIM, CDIM, x_r);
    gemm_f32<128,128,16,8,8,0,true><<<gBig, blk, 0, stream>>>(x, Wk, kbuf, MROWS, CDIM, CDIM, x_k);
    gemm_f32<128,128,16,8,8,0,true><<<gBig, blk, 0, stream>>>(x, Wv, vbuf, MROWS, CDIM, CDIM, x_v);
    // low-rank first stages
    gemm_f32<128, 64,16,8,4,1,true><<<gCol, blk, 0, stream>>>(x, w1, hwbuf, MROWS,  64, CDIM, x_w);
    gemm_f32<128, 32,16,8,2,0,true><<<gCol, blk, 0, stream>>>(x, v1, vwbuf, MROWS,  32, CDIM, x_v);
    gemm_f32<128, 64,16,8,4,0,true><<<gCol, blk, 0, stream>>>(x, a1, awbuf, MROWS,  64, CDIM, x_a);

    post_kernel<<<dim3(MROWS), dim3(1024), 0, stream>>>(
        hwbuf, vwbuf, awbuf, w2, v2, a2, w0, v0p, a0, k_k, k_a, vfirst,
        kbuf, vbuf, dbuf, kkbuf, bbuf);

    // chunked scan
    scan_pass1<<<dim3(NCHUNK, NBH), dim3(128), 0, stream>>>(
        dbuf, kbuf, vbuf, kkbuf, bbuf, Gbuf, Hbuf);
    scan_pass2<<<dim3(4, NBH), dim3(256), 0, stream>>>(Gbuf, Hbuf, S0buf);
    scan_pass3<<<dim3(NCHUNK, NBH), dim3(64), 0, stream>>>(
        rbuf, dbuf, kbuf, vbuf, kkbuf, bbuf, S0buf, ybuf);

    // g gate (after scan so gbuf could serve as Hbuf)
    gemm_f32<128,128,16,8,8,2,true><<<gCol, blk, 0, stream>>>(x, g1, ghbuf, MROWS, 128, CDIM, x_g);
    gemm_f32<128,128,16,8,8,0,false><<<gBig, blk, 0, stream>>>(ghbuf, g2, gbuf, MROWS, CDIM, 128, nullptr);

    gn_kernel<<<dim3(MROWS), dim3(1024), 0, stream>>>(rbuf, kbuf, vbuf, gbuf, r_k, lng, lnb, ybuf);

    gemm_f32<128,128,16,8,8,0,false><<<gBig, blk, 0, stream>>>(ybuf, Wo, outp, MROWS, CDIM, CDIM, nullptr);
}

// Round 4
// 847.440 us; speedup vs baseline: 7.2868x; 2.1597x over previous
//
#include <hip/hip_runtime.h>
#include <hip/hip_bf16.h>
#include <math.h>

#define TSEQ 2048
#define HEADS 16
#define HSZ 64
#define CDIM 1024
#define MROWS 4096   // B*T
#define CHUNK 64
#define NCHUNK (TSEQ/CHUNK)   // 32
#define NBH 32                // B*HEADS

typedef short bf16x8 __attribute__((ext_vector_type(8)));
typedef short bf16x4 __attribute__((ext_vector_type(4)));
typedef float f32x4 __attribute__((ext_vector_type(4)));

__device__ __forceinline__ float sigf(float x) { return 1.0f / (1.0f + expf(-x)); }

__device__ __forceinline__ short to_bf16(float f) {
    __hip_bfloat16 h = __float2bfloat16(f);
    return *reinterpret_cast<short*>(&h);
}

// ---------------------------------------------------------------------------
// Weight transpose + f32->bf16 convert:  W [K,N] f32  ->  Wt [N,K] bf16
// ---------------------------------------------------------------------------
__global__ __launch_bounds__(256)
void transpose_cvt(const float* __restrict__ W, short* __restrict__ Wt,
                   const int K, const int N)
{
    __shared__ float t[32][33];
    const int k0 = blockIdx.y * 32, n0 = blockIdx.x * 32;
    const int lx = threadIdx.x & 31, ly = threadIdx.x >> 5;   // ly 0..7
#pragma unroll
    for (int i = 0; i < 4; ++i)
        t[ly + i*8][lx] = W[(size_t)(k0 + ly + i*8)*N + n0 + lx];
    __syncthreads();
#pragma unroll
    for (int i = 0; i < 4; ++i)
        Wt[(size_t)(n0 + ly + i*8)*K + k0 + lx] = to_bf16(t[lx][ly + i*8]);
}

// ---------------------------------------------------------------------------
// bf16 MFMA GEMM:  C[M,N] = act( A'[M,K] @ Bt[N,K]^T )
// MIX:  A'[m,k] = cvt_bf16( x[m,k] + (x[m-1,k]-x[m,k])*mixv[k] ), x f32.
// else: A' is a pre-made bf16 [M,K] row-major buffer.
// Tile 128 x BN, BK=32; 4 waves; 16x16x32 MFMA.
// ACT: 0 none, 1 tanh, 2 sigmoid.  OBF16: write bf16 instead of f32.
// ---------------------------------------------------------------------------
template<int BN, int ACT, bool MIX, bool OBF16>
__global__ __launch_bounds__(256)
void gemm_mfma(const void* __restrict__ Aptr, const short* __restrict__ Bt,
               void* __restrict__ Cptr, const int M, const int N, const int K,
               const float* __restrict__ mixv)
{
    constexpr int BM = 128, BK = 32;
    constexpr int ASTR = BK + 8;                 // padded stride (bf16 elems)
    constexpr int NWC = (BN >= 128) ? 2 : 1;     // waves along N
    constexpr int NWR = 4 / NWC;                 // waves along M
    constexpr int WM = BM / NWR;                 // 64 or 32
    constexpr int WN = BN / NWC;                 // 64 / 64 / 32
    constexpr int AM = WM / 16;
    constexpr int AN = WN / 16;

    __shared__ short As[BM * ASTR];
    __shared__ short Bs[BN * ASTR];

    const int tid  = threadIdx.x;
    const int bm   = blockIdx.y * BM;
    const int bn   = blockIdx.x * BN;
    const int wid  = tid >> 6;
    const int lane = tid & 63;
    const int wr   = wid / NWC;
    const int wc   = wid % NWC;
    const int lrow = lane & 15;
    const int koff = (lane >> 4) * 8;

    f32x4 acc[AM][AN];
#pragma unroll
    for (int m = 0; m < AM; ++m)
#pragma unroll
        for (int n = 0; n < AN; ++n)
            acc[m][n] = (f32x4){0.f, 0.f, 0.f, 0.f};

    for (int k0 = 0; k0 < K; k0 += BK) {
        __syncthreads();
        // ---- stage A ----
        if (MIX) {
            const float* A = (const float*)Aptr;
#pragma unroll
            for (int p = 0; p < (BM*BK)/(256*4); ++p) {      // 4 passes
                const int flat = p*1024 + tid*4;
                const int row = flat >> 5;                    // /BK
                const int kc  = flat & 31;
                const int m   = bm + row;
                const float* xp = A + (size_t)m*K + k0 + kc;
                float4 xv = *(const float4*)xp;
                float4 xs = make_float4(0.f, 0.f, 0.f, 0.f);
                if ((m & (TSEQ-1)) != 0) xs = *(const float4*)(xp - K);
                const float4 mv = *(const float4*)(mixv + k0 + kc);
                xv.x += (xs.x - xv.x) * mv.x;
                xv.y += (xs.y - xv.y) * mv.y;
                xv.z += (xs.z - xv.z) * mv.z;
                xv.w += (xs.w - xv.w) * mv.w;
                bf16x4 o;
                o[0] = to_bf16(xv.x); o[1] = to_bf16(xv.y);
                o[2] = to_bf16(xv.z); o[3] = to_bf16(xv.w);
                *(bf16x4*)&As[row*ASTR + kc] = o;
            }
        } else {
            const short* A = (const short*)Aptr;
#pragma unroll
            for (int p = 0; p < (BM*BK)/(256*8); ++p) {      // 2 passes
                const int c = p*256 + tid;
                const int row = c >> 2;                       // /(BK/8)
                const int kc  = (c & 3) * 8;
                *(bf16x8*)&As[row*ASTR + kc] =
                    *(const bf16x8*)(A + (size_t)(bm+row)*K + k0 + kc);
            }
        }
        // ---- stage B (Bt is [N][K] bf16 row-major) ----
        {
            constexpr int CHUNKS = (BN*BK)/8;                // 512/256/128
#pragma unroll
            for (int p = 0; p < (CHUNKS + 255)/256; ++p) {
                const int c = p*256 + tid;
                if ((CHUNKS & 255) == 0 || c < CHUNKS) {
                    const int col = c >> 2;
                    const int kc  = (c & 3) * 8;
                    *(bf16x8*)&Bs[col*ASTR + kc] =
                        *(const bf16x8*)(Bt + (size_t)(bn+col)*K + k0 + kc);
                }
            }
        }
        __syncthreads();

        bf16x8 af[AM], bfv[AN];
#pragma unroll
        for (int m = 0; m < AM; ++m)
            af[m] = *(const bf16x8*)&As[(wr*WM + m*16 + lrow)*ASTR + koff];
#pragma unroll
        for (int n = 0; n < AN; ++n)
            bfv[n] = *(const bf16x8*)&Bs[(wc*WN + n*16 + lrow)*ASTR + koff];
#pragma unroll
        for (int m = 0; m < AM; ++m)
#pragma unroll
            for (int n = 0; n < AN; ++n)
                acc[m][n] = __builtin_amdgcn_mfma_f32_16x16x32_bf16(
                    af[m], bfv[n], acc[m][n], 0, 0, 0);
    }

    // ---- epilogue: D row = (lane>>4)*4 + j, col = lane&15 ----
    const int r0 = (lane >> 4) * 4;
#pragma unroll
    for (int m = 0; m < AM; ++m) {
#pragma unroll
        for (int n = 0; n < AN; ++n) {
#pragma unroll
            for (int j = 0; j < 4; ++j) {
                const int row = bm + wr*WM + m*16 + r0 + j;
                const int col = bn + wc*WN + n*16 + lrow;
                float vv = acc[m][n][j];
                if (ACT == 1) vv = tanhf(vv);
                else if (ACT == 2) vv = sigf(vv);
                if (OBF16) ((short*)Cptr)[(size_t)row*N + col] = to_bf16(vv);
                else       ((float*)Cptr)[(size_t)row*N + col] = vv;
            }
        }
    }
}

// ---------------------------------------------------------------------------
// Per-row post-processing
// ---------------------------------------------------------------------------
__global__ __launch_bounds__(1024)
void post_kernel(const float* __restrict__ hw, const float* __restrict__ vw,
                 const float* __restrict__ aw,
                 const float* __restrict__ w2, const float* __restrict__ v2,
                 const float* __restrict__ a2,
                 const float* __restrict__ w0, const float* __restrict__ v0p,
                 const float* __restrict__ a0p,
                 const float* __restrict__ k_k, const float* __restrict__ k_a,
                 const float* __restrict__ vfirst,
                 float* __restrict__ kio, float* __restrict__ vio,
                 float* __restrict__ dout, float* __restrict__ kkout,
                 float* __restrict__ bout)
{
    const int m = blockIdx.x;
    const int c = threadIdx.x;
    __shared__ float sh[160];
    if (c < 64)        sh[c] = hw[(size_t)m*64 + c];
    else if (c < 96)   sh[c] = vw[(size_t)m*32 + (c - 64)];
    else if (c < 160)  sh[c] = aw[(size_t)m*64 + (c - 96)];
    __syncthreads();

    float tw2 = 0.f, vv2 = 0.f, aa2 = 0.f;
    for (int j = 0; j < 64; ++j) tw2 = fmaf(sh[j],      w2[j*CDIM + c], tw2);
    for (int j = 0; j < 32; ++j) vv2 = fmaf(sh[64 + j], v2[j*CDIM + c], vv2);
    for (int j = 0; j < 64; ++j) aa2 = fmaf(sh[96 + j], a2[j*CDIM + c], aa2);

    const size_t o = (size_t)m*CDIM + c;
    const float z   = w0[c] + tw2;
    const float dec = expf(-0.6065306597126334f * sigf(z));
    const float sv  = sigf(v0p[c] + vv2);
    const float vold = vio[o];
    const float vnew = vold + (vfirst[o] - vold) * sv;
    const float a    = sigf(a0p[c] + aa2);
    const float kraw = kio[o];
    const float kkr  = kraw * k_k[c];
    float ss = kkr * kkr;
#pragma unroll
    for (int mask = 1; mask < 64; mask <<= 1) ss += __shfl_xor(ss, mask);
    const float inv = fmaxf(rsqrtf(ss + 1e-12f), 1e-12f);
    const float kkv = kkr * inv;

    dout[o]  = dec;
    vio[o]   = vnew;
    kio[o]   = kraw * (1.f + (a - 1.f) * k_a[c]);
    kkout[o] = kkv;
    bout[o]  = kkv * a;
}

// ---------------------------------------------------------------------------
// Scan pass 1: chunk transition G (64x64) and offset H (64x64).
// row[] only indexed with compile-time constants (rule #20).
// ---------------------------------------------------------------------------
__global__ __launch_bounds__(128)
void scan_pass1(const float* __restrict__ d, const float* __restrict__ k,
                const float* __restrict__ v, const float* __restrict__ kk,
                const float* __restrict__ bb,
                float* __restrict__ Gbuf, float* __restrict__ Hbuf)
{
    const int chunk = blockIdx.x;
    const int bh = blockIdx.y;
    const int b = bh >> 4, h = bh & 15;
    const int tid = threadIdx.x;
    const int lane = tid & 63;
    const int isH = tid >> 6;

    __shared__ float sv[4][64];   // 0=kk 1=d 2=bb 3=k

    float row[HSZ];
#pragma unroll
    for (int j = 0; j < HSZ; ++j)
        row[j] = (!isH && j == lane) ? 1.f : 0.f;   // identity for G, 0 for H

    size_t off = ((size_t)b*TSEQ + (size_t)chunk*CHUNK) * CDIM + h*HSZ;
    for (int t = 0; t < CHUNK; ++t, off += CDIM) {
        const float vi = isH ? v[off + lane] : 0.f;
        __syncthreads();
        if (!isH) { sv[0][lane] = kk[off + lane]; sv[2][lane] = bb[off + lane]; }
        else      { sv[1][lane] = d[off + lane];  sv[3][lane] = k[off + lane]; }
        __syncthreads();

        float g0 = 0.f, g1 = 0.f, g2 = 0.f, g3 = 0.f;
#pragma unroll
        for (int j4 = 0; j4 < 16; ++j4) {
            const float4 kv = *(const float4*)&sv[0][j4*4];
            g0 = fmaf(row[j4*4+0], kv.x, g0);
            g1 = fmaf(row[j4*4+1], kv.y, g1);
            g2 = fmaf(row[j4*4+2], kv.z, g2);
            g3 = fmaf(row[j4*4+3], kv.w, g3);
        }
        const float ga = -((g0 + g1) + (g2 + g3));

        if (isH) {
#pragma unroll
            for (int j4 = 0; j4 < 16; ++j4) {
                const float4 dv = *(const float4*)&sv[1][j4*4];
                const float4 bv = *(const float4*)&sv[2][j4*4];
                const float4 kv = *(const float4*)&sv[3][j4*4];
                row[j4*4+0] = fmaf(row[j4*4+0], dv.x, fmaf(ga, bv.x, vi * kv.x));
                row[j4*4+1] = fmaf(row[j4*4+1], dv.y, fmaf(ga, bv.y, vi * kv.y));
                row[j4*4+2] = fmaf(row[j4*4+2], dv.z, fmaf(ga, bv.z, vi * kv.z));
                row[j4*4+3] = fmaf(row[j4*4+3], dv.w, fmaf(ga, bv.w, vi * kv.w));
            }
        } else {
#pragma unroll
            for (int j4 = 0; j4 < 16; ++j4) {
                const float4 dv = *(const float4*)&sv[1][j4*4];
                const float4 bv = *(const float4*)&sv[2][j4*4];
                row[j4*4+0] = fmaf(row[j4*4+0], dv.x, ga * bv.x);
                row[j4*4+1] = fmaf(row[j4*4+1], dv.y, ga * bv.y);
                row[j4*4+2] = fmaf(row[j4*4+2], dv.z, ga * bv.z);
                row[j4*4+3] = fmaf(row[j4*4+3], dv.w, ga * bv.w);
            }
        }
    }

    float* dst = (isH ? Hbuf : Gbuf) + (((size_t)bh*NCHUNK + chunk)*HSZ + lane)*HSZ;
#pragma unroll
    for (int j4 = 0; j4 < 16; ++j4)
        *(float4*)&dst[j4*4] = make_float4(row[j4*4+0], row[j4*4+1], row[j4*4+2], row[j4*4+3]);
}

// ---------------------------------------------------------------------------
// Scan pass 2: propagate chunk-boundary states.
// ---------------------------------------------------------------------------
__global__ __launch_bounds__(256)
void scan_pass2(const float* __restrict__ Gbuf, const float* __restrict__ Hbuf,
                float* __restrict__ S0buf)
{
    const int rg = blockIdx.x;
    const int bh = blockIdx.y;
    const int tid = threadIdx.x;
    const int il = tid & 15;
    const int q4 = tid >> 4;
    const int row = rg*16 + il;

    __shared__ float Gs[64][68];
    __shared__ float Ssh[16][68];

    float frag[4] = {0.f, 0.f, 0.f, 0.f};
    *(float4*)&Ssh[il][q4*4] = make_float4(0.f, 0.f, 0.f, 0.f);

    for (int c = 0; c < NCHUNK; ++c) {
        const size_t mbase = ((size_t)bh*NCHUNK + c)*HSZ*HSZ;
#pragma unroll
        for (int p = 0; p < 4; ++p) {
            const int f = tid*16 + p*4;
            const int rr = f >> 6, cc = f & 63;
            *(float4*)&Gs[rr][cc] = *(const float4*)(Gbuf + mbase + f);
        }
        *(float4*)(S0buf + mbase + (size_t)row*HSZ + q4*4) =
            make_float4(frag[0], frag[1], frag[2], frag[3]);
        __syncthreads();

        float4 hv = *(const float4*)(Hbuf + mbase + (size_t)row*HSZ + q4*4);
        float a0 = hv.x, a1 = hv.y, a2 = hv.z, a3 = hv.w;
#pragma unroll
        for (int j = 0; j < 64; ++j) {
            const float sj = Ssh[il][j];
            const float4 gv = *(const float4*)&Gs[j][q4*4];
            a0 = fmaf(sj, gv.x, a0);
            a1 = fmaf(sj, gv.y, a1);
            a2 = fmaf(sj, gv.z, a2);
            a3 = fmaf(sj, gv.w, a3);
        }
        __syncthreads();
        frag[0] = a0; frag[1] = a1; frag[2] = a2; frag[3] = a3;
        *(float4*)&Ssh[il][q4*4] = make_float4(a0, a1, a2, a3);
    }
}

// ---------------------------------------------------------------------------
// Scan pass 3: replay each chunk from its known S0, producing y.
// ---------------------------------------------------------------------------
__global__ __launch_bounds__(64)
void scan_pass3(const float* __restrict__ r, const float* __restrict__ d,
                const float* __restrict__ k, const float* __restrict__ v,
                const float* __restrict__ kk, const float* __restrict__ bb,
                const float* __restrict__ S0buf, float* __restrict__ y)
{
    const int chunk = blockIdx.x;
    const int bh = blockIdx.y;
    const int b = bh >> 4, h = bh & 15;
    const int i = threadIdx.x;

    __shared__ float sv[5][64];   // 0=kk 1=d 2=bb 3=k 4=r

    float S[HSZ];
    const float* s0p = S0buf + (((size_t)bh*NCHUNK + chunk)*HSZ + i)*HSZ;
#pragma unroll
    for (int j4 = 0; j4 < 16; ++j4) {
        const float4 s4 = *(const float4*)&s0p[j4*4];
        S[j4*4+0] = s4.x; S[j4*4+1] = s4.y; S[j4*4+2] = s4.z; S[j4*4+3] = s4.w;
    }

    size_t off = ((size_t)b*TSEQ + (size_t)chunk*CHUNK) * CDIM + h*HSZ;
    for (int t = 0; t < CHUNK; ++t, off += CDIM) {
        const float vi = v[off + i];
        __syncthreads();
        sv[0][i] = kk[off + i];
        sv[1][i] = d[off + i];
        sv[2][i] = bb[off + i];
        sv[3][i] = k[off + i];
        sv[4][i] = r[off + i];
        __syncthreads();

        float g0 = 0.f, g1 = 0.f, g2 = 0.f, g3 = 0.f;
#pragma unroll
        for (int j4 = 0; j4 < 16; ++j4) {
            const float4 kv = *(const float4*)&sv[0][j4*4];
            g0 = fmaf(S[j4*4+0], kv.x, g0);
            g1 = fmaf(S[j4*4+1], kv.y, g1);
            g2 = fmaf(S[j4*4+2], kv.z, g2);
            g3 = fmaf(S[j4*4+3], kv.w, g3);
        }
        const float sa = -((g0 + g1) + (g2 + g3));

        float o0 = 0.f, o1 = 0.f, o2 = 0.f, o3 = 0.f;
#pragma unroll
        for (int j4 = 0; j4 < 16; ++j4) {
            const float4 dv = *(const float4*)&sv[1][j4*4];
            const float4 bv = *(const float4*)&sv[2][j4*4];
            const float4 kv = *(const float4*)&sv[3][j4*4];
            const float4 rv = *(const float4*)&sv[4][j4*4];
            const float s0n = fmaf(S[j4*4+0], dv.x, fmaf(sa, bv.x, vi * kv.x));
            const float s1n = fmaf(S[j4*4+1], dv.y, fmaf(sa, bv.y, vi * kv.y));
            const float s2n = fmaf(S[j4*4+2], dv.z, fmaf(sa, bv.z, vi * kv.z));
            const float s3n = fmaf(S[j4*4+3], dv.w, fmaf(sa, bv.w, vi * kv.w));
            S[j4*4+0] = s0n; S[j4*4+1] = s1n; S[j4*4+2] = s2n; S[j4*4+3] = s3n;
            o0 = fmaf(s0n, rv.x, o0);
            o1 = fmaf(s1n, rv.y, o1);
            o2 = fmaf(s2n, rv.z, o2);
            o3 = fmaf(s3n, rv.w, o3);
        }
        y[off + i] = (o0 + o1) + (o2 + o3);
    }
}

// ---------------------------------------------------------------------------
// GroupNorm + rank-1 rwkv residual + *g; writes bf16 (y*g) for the Wo GEMM.
// ---------------------------------------------------------------------------
__global__ __launch_bounds__(1024)
void gn_kernel(const float* __restrict__ r, const float* __restrict__ k,
               const float* __restrict__ v, const float* __restrict__ g,
               const float* __restrict__ rk, const float* __restrict__ gamma,
               const float* __restrict__ beta, const float* __restrict__ y,
               short* __restrict__ ybf)
{
    const int m = blockIdx.x;
    const int c = threadIdx.x;
    const size_t o = (size_t)m*CDIM + c;
    const float yv = y[o];
    float s1 = yv, s2 = yv*yv;
#pragma unroll
    for (int mask = 1; mask < 64; mask <<= 1) {
        s1 += __shfl_xor(s1, mask);
        s2 += __shfl_xor(s2, mask);
    }
    const float mu  = s1 * (1.f/HSZ);
    const float var = s2 * (1.f/HSZ) - mu*mu;
    const float gn  = (yv - mu) * rsqrtf(var + 0.00064f) * gamma[c] + beta[c];

    float p = r[o] * k[o] * rk[c];
#pragma unroll
    for (int mask = 1; mask < 64; mask <<= 1) p += __shfl_xor(p, mask);

    ybf[o] = to_bf16((gn + p * v[o]) * g[o]);
}

// ---------------------------------------------------------------------------
extern "C" void kernel_launch(void* const* d_in, const int* in_sizes, int n_in,
                              void* d_out, int out_size, void* d_ws, size_t ws_size,
                              hipStream_t stream)
{
    const float* x      = (const float*)d_in[0];
    const float* vfirst = (const float*)d_in[1];
    const float* x_r = (const float*)d_in[2];
    const float* x_w = (const float*)d_in[3];
    const float* x_k = (const float*)d_in[4];
    const float* x_v = (const float*)d_in[5];
    const float* x_a = (const float*)d_in[6];
    const float* x_g = (const float*)d_in[7];
    const float* w0  = (const float*)d_in[8];
    const float* w1  = (const float*)d_in[9];
    const float* w2  = (const float*)d_in[10];
    const float* a0  = (const float*)d_in[11];
    const float* a1  = (const float*)d_in[12];
    const float* a2  = (const float*)d_in[13];
    const float* v0p = (const float*)d_in[14];
    const float* v1  = (const float*)d_in[15];
    const float* v2  = (const float*)d_in[16];
    const float* g1  = (const float*)d_in[17];
    const float* g2  = (const float*)d_in[18];
    const float* k_k = (const float*)d_in[19];
    const float* k_a = (const float*)d_in[20];
    const float* r_k = (const float*)d_in[21];
    const float* Wr  = (const float*)d_in[22];
    const float* Wk  = (const float*)d_in[23];
    const float* Wv  = (const float*)d_in[24];
    const float* Wo  = (const float*)d_in[25];
    const float* lng = (const float*)d_in[26];
    const float* lnb = (const float*)d_in[27];
    float* outp = (float*)d_out;

    float* ws = (float*)d_ws;
    const size_t BIG = (size_t)MROWS * CDIM;   // 4 Mi floats = 16 MB
    float* rbuf  = ws + 0*BIG;
    float* kbuf  = ws + 1*BIG;
    float* vbuf  = ws + 2*BIG;
    float* dbuf  = ws + 3*BIG;   // after pass3: ybf (bf16) at +0, ghbf at +8MB
    float* kkbuf = ws + 4*BIG;
    float* bbuf  = ws + 5*BIG;
    float* gbuf  = ws + 6*BIG;   // Hbuf during scan
    float* ybuf  = ws + 7*BIG;   // Gbuf during scan
    float* hwbuf = ws + 8*BIG;                  // 4096*64
    float* vwbuf = hwbuf + (size_t)MROWS*64;    // 4096*32
    float* awbuf = vwbuf + (size_t)MROWS*32;    // 4096*64
    short* wT    = (short*)(awbuf + (size_t)MROWS*64);
    short* WrT = wT;                          // [1024][1024]
    short* WkT = WrT + (size_t)CDIM*CDIM;
    short* WvT = WkT + (size_t)CDIM*CDIM;
    short* WoT = WvT + (size_t)CDIM*CDIM;
    short* g1T = WoT + (size_t)CDIM*CDIM;     // [128][1024]
    short* g2T = g1T + (size_t)128*CDIM;      // [1024][128]
    short* w1T = g2T + (size_t)CDIM*128;      // [64][1024]
    short* v1T = w1T + (size_t)64*CDIM;       // [32][1024]
    short* a1T = v1T + (size_t)32*CDIM;       // [64][1024]

    float* Gbuf  = ybuf;
    float* Hbuf  = gbuf;
    float* S0buf = outp;                      // overwritten by final GEMM
    short* ybf   = (short*)dbuf;              // dbuf dead after pass3
    short* ghbf  = (short*)dbuf + 4*1024*1024;

    const dim3 blk(256);

    // weight transpose+convert (f32 [K,N] -> bf16 [N,K])
    transpose_cvt<<<dim3(CDIM/32, CDIM/32), blk, 0, stream>>>(Wr, WrT, CDIM, CDIM);
    transpose_cvt<<<dim3(CDIM/32, CDIM/32), blk, 0, stream>>>(Wk, WkT, CDIM, CDIM);
    transpose_cvt<<<dim3(CDIM/32, CDIM/32), blk, 0, stream>>>(Wv, WvT, CDIM, CDIM);
    transpose_cvt<<<dim3(CDIM/32, CDIM/32), blk, 0, stream>>>(Wo, WoT, CDIM, CDIM);
    transpose_cvt<<<dim3(128/32,  CDIM/32), blk, 0, stream>>>(g1, g1T, CDIM, 128);
    transpose_cvt<<<dim3(CDIM/32, 128/32),  blk, 0, stream>>>(g2, g2T, 128, CDIM);
    transpose_cvt<<<dim3(64/32,   CDIM/32), blk, 0, stream>>>(w1, w1T, CDIM, 64);
    transpose_cvt<<<dim3(32/32,   CDIM/32), blk, 0, stream>>>(v1, v1T, CDIM, 32);
    transpose_cvt<<<dim3(64/32,   CDIM/32), blk, 0, stream>>>(a1, a1T, CDIM, 64);

    const dim3 gBig(CDIM/128, MROWS/128);    // (8, 32)
    const dim3 gOne(1, MROWS/128);           // (1, 32)

    // big projections (mix fused into A-staging)
    gemm_mfma<128,0,true,false><<<gBig, blk, 0, stream>>>(x, WrT, rbuf, MROWS, CDIM, CDIM, x_r);
    gemm_mfma<128,0,true,false><<<gBig, blk, 0, stream>>>(x, WkT, kbuf, MROWS, CDIM, CDIM, x_k);
    gemm_mfma<128,0,true,false><<<gBig, blk, 0, stream>>>(x, WvT, vbuf, MROWS, CDIM, CDIM, x_v);
    // low-rank first stages
    gemm_mfma< 64,1,true,false><<<gOne, blk, 0, stream>>>(x, w1T, hwbuf, MROWS,  64, CDIM, x_w);
    gemm_mfma< 32,0,true,false><<<gOne, blk, 0, stream>>>(x, v1T, vwbuf, MROWS,  32, CDIM, x_v);
    gemm_mfma< 64,0,true,false><<<gOne, blk, 0, stream>>>(x, a1T, awbuf, MROWS,  64, CDIM, x_a);

    post_kernel<<<dim3(MROWS), dim3(1024), 0, stream>>>(
        hwbuf, vwbuf, awbuf, w2, v2, a2, w0, v0p, a0, k_k, k_a, vfirst,
        kbuf, vbuf, dbuf, kkbuf, bbuf);

    // chunked scan
    scan_pass1<<<dim3(NCHUNK, NBH), dim3(128), 0, stream>>>(
        dbuf, kbuf, vbuf, kkbuf, bbuf, Gbuf, Hbuf);
    scan_pass2<<<dim3(4, NBH), dim3(256), 0, stream>>>(Gbuf, Hbuf, S0buf);
    scan_pass3<<<dim3(NCHUNK, NBH), dim3(64), 0, stream>>>(
        rbuf, dbuf, kbuf, vbuf, kkbuf, bbuf, S0buf, ybuf);

    // g gate (after pass3: ghbf lives in dbuf, dbuf now dead)
    gemm_mfma<128,2,true,true ><<<gOne, blk, 0, stream>>>(x, g1T, ghbf, MROWS, 128, CDIM, x_g);
    gemm_mfma<128,0,false,false><<<gBig, blk, 0, stream>>>(ghbf, g2T, gbuf, MROWS, CDIM, 128, nullptr);

    gn_kernel<<<dim3(MROWS), dim3(1024), 0, stream>>>(
        rbuf, kbuf, vbuf, gbuf, r_k, lng, lnb, ybuf, ybf);

    gemm_mfma<128,0,false,false><<<gBig, blk, 0, stream>>>(ybf, WoT, outp, MROWS, CDIM, CDIM, nullptr);
}

// Round 5
// 758.735 us; speedup vs baseline: 8.1387x; 1.1169x over previous
//
#include <hip/hip_runtime.h>
#include <hip/hip_bf16.h>
#include <math.h>

#define TSEQ 2048
#define HEADS 16
#define HSZ 64
#define CDIM 1024
#define MROWS 4096   // B*T
#define CHUNK 64
#define NCHUNK (TSEQ/CHUNK)   // 32
#define NBH 32                // B*HEADS
#define LSTR 68               // LDS row stride (shorts) for 64-wide bf16 mats

typedef short bf16x8 __attribute__((ext_vector_type(8)));
typedef short bf16x4 __attribute__((ext_vector_type(4)));
typedef float f32x4 __attribute__((ext_vector_type(4)));

__device__ __forceinline__ float sigf(float x) { return 1.0f / (1.0f + expf(-x)); }

__device__ __forceinline__ short to_bf16(float f) {
    __hip_bfloat16 h = __float2bfloat16(f);
    return *reinterpret_cast<short*>(&h);
}

// ---------------------------------------------------------------------------
// Weight transpose + f32->bf16 convert:  W [K,N] f32  ->  Wt [N,K] bf16
// ---------------------------------------------------------------------------
__global__ __launch_bounds__(256)
void transpose_cvt(const float* __restrict__ W, short* __restrict__ Wt,
                   const int K, const int N)
{
    __shared__ float t[32][33];
    const int k0 = blockIdx.y * 32, n0 = blockIdx.x * 32;
    const int lx = threadIdx.x & 31, ly = threadIdx.x >> 5;   // ly 0..7
#pragma unroll
    for (int i = 0; i < 4; ++i)
        t[ly + i*8][lx] = W[(size_t)(k0 + ly + i*8)*N + n0 + lx];
    __syncthreads();
#pragma unroll
    for (int i = 0; i < 4; ++i)
        Wt[(size_t)(n0 + ly + i*8)*K + k0 + lx] = to_bf16(t[lx][ly + i*8]);
}

// ---------------------------------------------------------------------------
// bf16 MFMA GEMM:  C[M,N] = act( A'[M,K] @ Bt[N,K]^T )   (round-4, verified)
// ---------------------------------------------------------------------------
template<int BN, int ACT, bool MIX, bool OBF16>
__global__ __launch_bounds__(256)
void gemm_mfma(const void* __restrict__ Aptr, const short* __restrict__ Bt,
               void* __restrict__ Cptr, const int M, const int N, const int K,
               const float* __restrict__ mixv)
{
    constexpr int BM = 128, BK = 32;
    constexpr int ASTR = BK + 8;
    constexpr int NWC = (BN >= 128) ? 2 : 1;
    constexpr int NWR = 4 / NWC;
    constexpr int WM = BM / NWR;
    constexpr int WN = BN / NWC;
    constexpr int AM = WM / 16;
    constexpr int AN = WN / 16;

    __shared__ short As[BM * ASTR];
    __shared__ short Bs[BN * ASTR];

    const int tid  = threadIdx.x;
    const int bm   = blockIdx.y * BM;
    const int bn   = blockIdx.x * BN;
    const int wid  = tid >> 6;
    const int lane = tid & 63;
    const int wr   = wid / NWC;
    const int wc   = wid % NWC;
    const int lrow = lane & 15;
    const int koff = (lane >> 4) * 8;

    f32x4 acc[AM][AN];
#pragma unroll
    for (int m = 0; m < AM; ++m)
#pragma unroll
        for (int n = 0; n < AN; ++n)
            acc[m][n] = (f32x4){0.f, 0.f, 0.f, 0.f};

    for (int k0 = 0; k0 < K; k0 += BK) {
        __syncthreads();
        if (MIX) {
            const float* A = (const float*)Aptr;
#pragma unroll
            for (int p = 0; p < (BM*BK)/(256*4); ++p) {
                const int flat = p*1024 + tid*4;
                const int row = flat >> 5;
                const int kc  = flat & 31;
                const int m   = bm + row;
                const float* xp = A + (size_t)m*K + k0 + kc;
                float4 xv = *(const float4*)xp;
                float4 xs = make_float4(0.f, 0.f, 0.f, 0.f);
                if ((m & (TSEQ-1)) != 0) xs = *(const float4*)(xp - K);
                const float4 mv = *(const float4*)(mixv + k0 + kc);
                xv.x += (xs.x - xv.x) * mv.x;
                xv.y += (xs.y - xv.y) * mv.y;
                xv.z += (xs.z - xv.z) * mv.z;
                xv.w += (xs.w - xv.w) * mv.w;
                bf16x4 o;
                o[0] = to_bf16(xv.x); o[1] = to_bf16(xv.y);
                o[2] = to_bf16(xv.z); o[3] = to_bf16(xv.w);
                *(bf16x4*)&As[row*ASTR + kc] = o;
            }
        } else {
            const short* A = (const short*)Aptr;
#pragma unroll
            for (int p = 0; p < (BM*BK)/(256*8); ++p) {
                const int c = p*256 + tid;
                const int row = c >> 2;
                const int kc  = (c & 3) * 8;
                *(bf16x8*)&As[row*ASTR + kc] =
                    *(const bf16x8*)(A + (size_t)(bm+row)*K + k0 + kc);
            }
        }
        {
            constexpr int CHUNKS = (BN*BK)/8;
#pragma unroll
            for (int p = 0; p < (CHUNKS + 255)/256; ++p) {
                const int c = p*256 + tid;
                if ((CHUNKS & 255) == 0 || c < CHUNKS) {
                    const int col = c >> 2;
                    const int kc  = (c & 3) * 8;
                    *(bf16x8*)&Bs[col*ASTR + kc] =
                        *(const bf16x8*)(Bt + (size_t)(bn+col)*K + k0 + kc);
                }
            }
        }
        __syncthreads();

        bf16x8 af[AM], bfv[AN];
#pragma unroll
        for (int m = 0; m < AM; ++m)
            af[m] = *(const bf16x8*)&As[(wr*WM + m*16 + lrow)*ASTR + koff];
#pragma unroll
        for (int n = 0; n < AN; ++n)
            bfv[n] = *(const bf16x8*)&Bs[(wc*WN + n*16 + lrow)*ASTR + koff];
#pragma unroll
        for (int m = 0; m < AM; ++m)
#pragma unroll
            for (int n = 0; n < AN; ++n)
                acc[m][n] = __builtin_amdgcn_mfma_f32_16x16x32_bf16(
                    af[m], bfv[n], acc[m][n], 0, 0, 0);
    }

    const int r0 = (lane >> 4) * 4;
#pragma unroll
    for (int m = 0; m < AM; ++m) {
#pragma unroll
        for (int n = 0; n < AN; ++n) {
#pragma unroll
            for (int j = 0; j < 4; ++j) {
                const int row = bm + wr*WM + m*16 + r0 + j;
                const int col = bn + wc*WN + n*16 + lrow;
                float vv = acc[m][n][j];
                if (ACT == 1) vv = tanhf(vv);
                else if (ACT == 2) vv = sigf(vv);
                if (OBF16) ((short*)Cptr)[(size_t)row*N + col] = to_bf16(vv);
                else       ((float*)Cptr)[(size_t)row*N + col] = vv;
            }
        }
    }
}

// ---------------------------------------------------------------------------
// Per-row post-processing (unchanged)
// ---------------------------------------------------------------------------
__global__ __launch_bounds__(1024)
void post_kernel(const float* __restrict__ hw, const float* __restrict__ vw,
                 const float* __restrict__ aw,
                 const float* __restrict__ w2, const float* __restrict__ v2,
                 const float* __restrict__ a2,
                 const float* __restrict__ w0, const float* __restrict__ v0p,
                 const float* __restrict__ a0p,
                 const float* __restrict__ k_k, const float* __restrict__ k_a,
                 const float* __restrict__ vfirst,
                 float* __restrict__ kio, float* __restrict__ vio,
                 float* __restrict__ dout, float* __restrict__ kkout,
                 float* __restrict__ bout)
{
    const int m = blockIdx.x;
    const int c = threadIdx.x;
    __shared__ float sh[160];
    if (c < 64)        sh[c] = hw[(size_t)m*64 + c];
    else if (c < 96)   sh[c] = vw[(size_t)m*32 + (c - 64)];
    else if (c < 160)  sh[c] = aw[(size_t)m*64 + (c - 96)];
    __syncthreads();

    float tw2 = 0.f, vv2 = 0.f, aa2 = 0.f;
    for (int j = 0; j < 64; ++j) tw2 = fmaf(sh[j],      w2[j*CDIM + c], tw2);
    for (int j = 0; j < 32; ++j) vv2 = fmaf(sh[64 + j], v2[j*CDIM + c], vv2);
    for (int j = 0; j < 64; ++j) aa2 = fmaf(sh[96 + j], a2[j*CDIM + c], aa2);

    const size_t o = (size_t)m*CDIM + c;
    const float z   = w0[c] + tw2;
    const float dec = expf(-0.6065306597126334f * sigf(z));
    const float sv  = sigf(v0p[c] + vv2);
    const float vold = vio[o];
    const float vnew = vold + (vfirst[o] - vold) * sv;
    const float a    = sigf(a0p[c] + aa2);
    const float kraw = kio[o];
    const float kkr  = kraw * k_k[c];
    float ss = kkr * kkr;
#pragma unroll
    for (int mask = 1; mask < 64; mask <<= 1) ss += __shfl_xor(ss, mask);
    const float inv = fmaxf(rsqrtf(ss + 1e-12f), 1e-12f);
    const float kkv = kkr * inv;

    dout[o]  = dec;
    vio[o]   = vnew;
    kio[o]   = kraw * (1.f + (a - 1.f) * k_a[c]);
    kkout[o] = kkv;
    bout[o]  = kkv * a;
}

// ---------------------------------------------------------------------------
// Scan pass 1 (scalar, unchanged): chunk transition G and offset H.
// ---------------------------------------------------------------------------
__global__ __launch_bounds__(128)
void scan_pass1(const float* __restrict__ d, const float* __restrict__ k,
                const float* __restrict__ v, const float* __restrict__ kk,
                const float* __restrict__ bb,
                float* __restrict__ Gbuf, float* __restrict__ Hbuf)
{
    const int chunk = blockIdx.x;
    const int bh = blockIdx.y;
    const int b = bh >> 4, h = bh & 15;
    const int tid = threadIdx.x;
    const int lane = tid & 63;
    const int isH = tid >> 6;

    __shared__ float sv[4][64];   // 0=kk 1=d 2=bb 3=k

    float row[HSZ];
#pragma unroll
    for (int j = 0; j < HSZ; ++j)
        row[j] = (!isH && j == lane) ? 1.f : 0.f;

    size_t off = ((size_t)b*TSEQ + (size_t)chunk*CHUNK) * CDIM + h*HSZ;
    for (int t = 0; t < CHUNK; ++t, off += CDIM) {
        const float vi = isH ? v[off + lane] : 0.f;
        __syncthreads();
        if (!isH) { sv[0][lane] = kk[off + lane]; sv[2][lane] = bb[off + lane]; }
        else      { sv[1][lane] = d[off + lane];  sv[3][lane] = k[off + lane]; }
        __syncthreads();

        float g0 = 0.f, g1 = 0.f, g2 = 0.f, g3 = 0.f;
#pragma unroll
        for (int j4 = 0; j4 < 16; ++j4) {
            const float4 kv = *(const float4*)&sv[0][j4*4];
            g0 = fmaf(row[j4*4+0], kv.x, g0);
            g1 = fmaf(row[j4*4+1], kv.y, g1);
            g2 = fmaf(row[j4*4+2], kv.z, g2);
            g3 = fmaf(row[j4*4+3], kv.w, g3);
        }
        const float ga = -((g0 + g1) + (g2 + g3));

        if (isH) {
#pragma unroll
            for (int j4 = 0; j4 < 16; ++j4) {
                const float4 dv = *(const float4*)&sv[1][j4*4];
                const float4 bv = *(const float4*)&sv[2][j4*4];
                const float4 kv = *(const float4*)&sv[3][j4*4];
                row[j4*4+0] = fmaf(row[j4*4+0], dv.x, fmaf(ga, bv.x, vi * kv.x));
                row[j4*4+1] = fmaf(row[j4*4+1], dv.y, fmaf(ga, bv.y, vi * kv.y));
                row[j4*4+2] = fmaf(row[j4*4+2], dv.z, fmaf(ga, bv.z, vi * kv.z));
                row[j4*4+3] = fmaf(row[j4*4+3], dv.w, fmaf(ga, bv.w, vi * kv.w));
            }
        } else {
#pragma unroll
            for (int j4 = 0; j4 < 16; ++j4) {
                const float4 dv = *(const float4*)&sv[1][j4*4];
                const float4 bv = *(const float4*)&sv[2][j4*4];
                row[j4*4+0] = fmaf(row[j4*4+0], dv.x, ga * bv.x);
                row[j4*4+1] = fmaf(row[j4*4+1], dv.y, ga * bv.y);
                row[j4*4+2] = fmaf(row[j4*4+2], dv.z, ga * bv.z);
                row[j4*4+3] = fmaf(row[j4*4+3], dv.w, ga * bv.w);
            }
        }
    }

    float* dst = (isH ? Hbuf : Gbuf) + (((size_t)bh*NCHUNK + chunk)*HSZ + lane)*HSZ;
#pragma unroll
    for (int j4 = 0; j4 < 16; ++j4)
        *(float4*)&dst[j4*4] = make_float4(row[j4*4+0], row[j4*4+1], row[j4*4+2], row[j4*4+3]);
}

// ---------------------------------------------------------------------------
// Scan pass 2 (unchanged): propagate chunk-boundary states.
// ---------------------------------------------------------------------------
__global__ __launch_bounds__(256)
void scan_pass2(const float* __restrict__ Gbuf, const float* __restrict__ Hbuf,
                float* __restrict__ S0buf)
{
    const int rg = blockIdx.x;
    const int bh = blockIdx.y;
    const int tid = threadIdx.x;
    const int il = tid & 15;
    const int q4 = tid >> 4;
    const int row = rg*16 + il;

    __shared__ float Gs[64][68];
    __shared__ float Ssh[16][68];

    float frag[4] = {0.f, 0.f, 0.f, 0.f};
    *(float4*)&Ssh[il][q4*4] = make_float4(0.f, 0.f, 0.f, 0.f);

    for (int c = 0; c < NCHUNK; ++c) {
        const size_t mbase = ((size_t)bh*NCHUNK + c)*HSZ*HSZ;
#pragma unroll
        for (int p = 0; p < 4; ++p) {
            const int f = tid*16 + p*4;
            const int rr = f >> 6, cc = f & 63;
            *(float4*)&Gs[rr][cc] = *(const float4*)(Gbuf + mbase + f);
        }
        *(float4*)(S0buf + mbase + (size_t)row*HSZ + q4*4) =
            make_float4(frag[0], frag[1], frag[2], frag[3]);
        __syncthreads();

        float4 hv = *(const float4*)(Hbuf + mbase + (size_t)row*HSZ + q4*4);
        float a0 = hv.x, a1 = hv.y, a2 = hv.z, a3 = hv.w;
#pragma unroll
        for (int j = 0; j < 64; ++j) {
            const float sj = Ssh[il][j];
            const float4 gv = *(const float4*)&Gs[j][q4*4];
            a0 = fmaf(sj, gv.x, a0);
            a1 = fmaf(sj, gv.y, a1);
            a2 = fmaf(sj, gv.z, a2);
            a3 = fmaf(sj, gv.w, a3);
        }
        __syncthreads();
        frag[0] = a0; frag[1] = a1; frag[2] = a2; frag[3] = a3;
        *(float4*)&Ssh[il][q4*4] = make_float4(a0, a1, a2, a3);
    }
}

// ---------------------------------------------------------------------------
// Pass-3 MFMA helpers: 64x64x64 GEMM by ONE wave, C[M,N] += A · B^T form.
// Both operands row-major with k contiguous, LDS stride LSTR shorts.
// ---------------------------------------------------------------------------
__device__ __forceinline__ void zero44(f32x4 a[4][4]) {
#pragma unroll
    for (int m = 0; m < 4; ++m)
#pragma unroll
        for (int n = 0; n < 4; ++n) a[m][n] = (f32x4){0.f, 0.f, 0.f, 0.f};
}

__device__ __forceinline__ void mm_nt_lds(const short* __restrict__ Ab,
                                          const short* __restrict__ Bb,
                                          f32x4 acc[4][4], const int lane)
{
    const int lrow = lane & 15;
    const int ko   = (lane >> 4) * 8;
#pragma unroll
    for (int kh = 0; kh < 2; ++kh) {
        bf16x8 af[4], bfv[4];
#pragma unroll
        for (int m = 0; m < 4; ++m)
            af[m] = *(const bf16x8*)&Ab[(m*16 + lrow)*LSTR + kh*32 + ko];
#pragma unroll
        for (int n = 0; n < 4; ++n)
            bfv[n] = *(const bf16x8*)&Bb[(n*16 + lrow)*LSTR + kh*32 + ko];
#pragma unroll
        for (int m = 0; m < 4; ++m)
#pragma unroll
            for (int n = 0; n < 4; ++n)
                acc[m][n] = __builtin_amdgcn_mfma_f32_16x16x32_bf16(
                    af[m], bfv[n], acc[m][n], 0, 0, 0);
    }
}

// B operand read from GLOBAL f32 [64][64] row-major, converted on the fly
__device__ __forceinline__ void mm_nt_gf32(const short* __restrict__ Ab,
                                           const float* __restrict__ Bg,
                                           f32x4 acc[4][4], const int lane)
{
    const int lrow = lane & 15;
    const int ko   = (lane >> 4) * 8;
#pragma unroll
    for (int kh = 0; kh < 2; ++kh) {
        bf16x8 af[4], bfv[4];
#pragma unroll
        for (int m = 0; m < 4; ++m)
            af[m] = *(const bf16x8*)&Ab[(m*16 + lrow)*LSTR + kh*32 + ko];
#pragma unroll
        for (int n = 0; n < 4; ++n) {
            const float* p = Bg + (size_t)(n*16 + lrow)*64 + kh*32 + ko;
            const float4 u0 = *(const float4*)p;
            const float4 u1 = *(const float4*)(p + 4);
            bf16x8 bv;
            bv[0] = to_bf16(u0.x); bv[1] = to_bf16(u0.y);
            bv[2] = to_bf16(u0.z); bv[3] = to_bf16(u0.w);
            bv[4] = to_bf16(u1.x); bv[5] = to_bf16(u1.y);
            bv[6] = to_bf16(u1.z); bv[7] = to_bf16(u1.w);
            bfv[n] = bv;
        }
#pragma unroll
        for (int m = 0; m < 4; ++m)
#pragma unroll
            for (int n = 0; n < 4; ++n)
                acc[m][n] = __builtin_amdgcn_mfma_f32_16x16x32_bf16(
                    af[m], bfv[n], acc[m][n], 0, 0, 0);
    }
}

// store accumulators to LDS bf16. MASK: 0 none, 1 strict lower (col<row),
// 2 inclusive lower (col<=row). Optional straight [row][col] and/or
// transposed [col][row] targets.
template<int MASK, bool WRN, bool WRT>
__device__ __forceinline__ void acc_store(const f32x4 acc[4][4],
                                          short* __restrict__ dst,
                                          short* __restrict__ dstT,
                                          const int lane)
{
    const int r0 = (lane >> 4) * 4;
    const int c0 = lane & 15;
#pragma unroll
    for (int m = 0; m < 4; ++m)
#pragma unroll
        for (int n = 0; n < 4; ++n)
#pragma unroll
            for (int j = 0; j < 4; ++j) {
                const int row = m*16 + r0 + j;
                const int col = n*16 + c0;
                float vv = acc[m][n][j];
                if (MASK == 1 && col >= row) vv = 0.f;
                if (MASK == 2 && col >  row) vv = 0.f;
                const short bv = to_bf16(vv);
                if (WRN) dst [row*LSTR + col] = bv;
                if (WRT) dstT[col*LSTR + row] = bv;
            }
}

// ---------------------------------------------------------------------------
// Scan pass 3, MFMA chunk form. One wave per (chunk, bh).
//   A = stril(Ah Bh^T), C = stril(Ah Kh^T)
//   W = (I-A)^{-1} (Ah S0^T + C V)   via (I-N)^{-1} = prod(I + N^{2^k})
//   Out = Rh S0^T + tril(Rh Bh^T) W + tril(Rh Kh^T) V
// where Ah = -kk*c_prev, Bh = b/c, Kh = k/c, Rh = r*c (c = cum decay).
// ---------------------------------------------------------------------------
__global__ __launch_bounds__(64)
void scan_pass3_mfma(const float* __restrict__ r, const float* __restrict__ d,
                     const float* __restrict__ k, const float* __restrict__ v,
                     const float* __restrict__ kk, const float* __restrict__ bb,
                     const float* __restrict__ S0buf, float* __restrict__ y)
{
    __shared__ short Ah[64*LSTR], Bh[64*LSTR], Kh[64*LSTR], Rh[64*LSTR];
    __shared__ short Vt[64*LSTR], Cb[64*LSTR], Nb[64*LSTR], Nt[64*LSTR], Xt[64*LSTR];

    const int chunk = blockIdx.x;
    const int bh = blockIdx.y;
    const int b = bh >> 4, h = bh & 15;
    const int lane = threadIdx.x;

    // ---- build hatted matrices; lane = feature j, sequential over t ----
    size_t off = ((size_t)b*TSEQ + (size_t)chunk*CHUNK)*CDIM + h*HSZ + lane;
    float run = 0.f;                       // log cumulative decay csum_t
    for (int t = 0; t < CHUNK; ++t, off += CDIM) {
        const float de    = d[off];
        const float cprev = run;
        run += logf(de);
        Ah[t*LSTR + lane] = to_bf16(-kk[off] * expf(cprev));
        Bh[t*LSTR + lane] = to_bf16(bb[off] * expf(-run));
        Kh[t*LSTR + lane] = to_bf16(k[off]  * expf(-run));
        Rh[t*LSTR + lane] = to_bf16(r[off]  * expf(run));
        Vt[lane*LSTR + t] = to_bf16(v[off]);
    }
    __syncthreads();

    const float* S0g = S0buf + ((size_t)bh*NCHUNK + chunk)*HSZ*HSZ;

    f32x4 acc[4][4], xacc[4][4];

    // A -> Nb/Nt ; C -> Cb   (both strictly lower)
    zero44(acc);  mm_nt_lds(Ah, Bh, acc, lane);
    acc_store<1, true, true>(acc, Nb, Nt, lane);
    zero44(acc);  mm_nt_lds(Ah, Kh, acc, lane);
    acc_store<1, true, false>(acc, Cb, nullptr, lane);
    __syncthreads();

    // X = Ah S0^T + C V   (RHS of the solve; stays in accumulators)
    zero44(xacc);
    mm_nt_gf32(Ah, S0g, xacc, lane);
    mm_nt_lds(Cb, Vt, xacc, lane);
    acc_store<0, false, true>(xacc, nullptr, Xt, lane);
    __syncthreads();

    // Neumann doubling: X <- (I + N^{2^k}) X ; N <- N^2   (exact, N^64 = 0)
#pragma unroll 1
    for (int rd = 0; rd < 6; ++rd) {
        mm_nt_lds(Nb, Xt, xacc, lane);              // xacc += N * X
        if (rd < 5) { zero44(acc); mm_nt_lds(Nb, Nt, acc, lane); }  // N^2
        __syncthreads();                            // all reads complete
        acc_store<0, false, true>(xacc, nullptr, Xt, lane);
        if (rd < 5) acc_store<0, true, true>(acc, Nb, Nt, lane);
        __syncthreads();
    }
    // Xt now holds W^T (bf16)

    // P1 = tril(Rh Bh^T) -> Cb ; P2 = tril(Rh Kh^T) -> Nb  (inclusive)
    zero44(acc);  mm_nt_lds(Rh, Bh, acc, lane);
    acc_store<2, true, false>(acc, Cb, nullptr, lane);
    zero44(acc);  mm_nt_lds(Rh, Kh, acc, lane);
    acc_store<2, true, false>(acc, Nb, nullptr, lane);
    __syncthreads();

    // Out = Rh S0^T + P1 W + P2 V
    zero44(acc);
    mm_nt_gf32(Rh, S0g, acc, lane);
    mm_nt_lds(Cb, Xt, acc, lane);
    mm_nt_lds(Nb, Vt, acc, lane);

    const int r0 = (lane >> 4) * 4;
    const int c0 = lane & 15;
    float* yb = y + ((size_t)b*TSEQ + (size_t)chunk*CHUNK)*CDIM + h*HSZ;
#pragma unroll
    for (int m = 0; m < 4; ++m)
#pragma unroll
        for (int n = 0; n < 4; ++n)
#pragma unroll
            for (int j = 0; j < 4; ++j)
                yb[(size_t)(m*16 + r0 + j)*CDIM + n*16 + c0] = acc[m][n][j];
}

// ---------------------------------------------------------------------------
// GroupNorm + rank-1 rwkv residual + *g; writes bf16 (y*g) for the Wo GEMM.
// ---------------------------------------------------------------------------
__global__ __launch_bounds__(1024)
void gn_kernel(const float* __restrict__ r, const float* __restrict__ k,
               const float* __restrict__ v, const float* __restrict__ g,
               const float* __restrict__ rk, const float* __restrict__ gamma,
               const float* __restrict__ beta, const float* __restrict__ y,
               short* __restrict__ ybf)
{
    const int m = blockIdx.x;
    const int c = threadIdx.x;
    const size_t o = (size_t)m*CDIM + c;
    const float yv = y[o];
    float s1 = yv, s2 = yv*yv;
#pragma unroll
    for (int mask = 1; mask < 64; mask <<= 1) {
        s1 += __shfl_xor(s1, mask);
        s2 += __shfl_xor(s2, mask);
    }
    const float mu  = s1 * (1.f/HSZ);
    const float var = s2 * (1.f/HSZ) - mu*mu;
    const float gn  = (yv - mu) * rsqrtf(var + 0.00064f) * gamma[c] + beta[c];

    float p = r[o] * k[o] * rk[c];
#pragma unroll
    for (int mask = 1; mask < 64; mask <<= 1) p += __shfl_xor(p, mask);

    ybf[o] = to_bf16((gn + p * v[o]) * g[o]);
}

// ---------------------------------------------------------------------------
extern "C" void kernel_launch(void* const* d_in, const int* in_sizes, int n_in,
                              void* d_out, int out_size, void* d_ws, size_t ws_size,
                              hipStream_t stream)
{
    const float* x      = (const float*)d_in[0];
    const float* vfirst = (const float*)d_in[1];
    const float* x_r = (const float*)d_in[2];
    const float* x_w = (const float*)d_in[3];
    const float* x_k = (const float*)d_in[4];
    const float* x_v = (const float*)d_in[5];
    const float* x_a = (const float*)d_in[6];
    const float* x_g = (const float*)d_in[7];
    const float* w0  = (const float*)d_in[8];
    const float* w1  = (const float*)d_in[9];
    const float* w2  = (const float*)d_in[10];
    const float* a0  = (const float*)d_in[11];
    const float* a1  = (const float*)d_in[12];
    const float* a2  = (const float*)d_in[13];
    const float* v0p = (const float*)d_in[14];
    const float* v1  = (const float*)d_in[15];
    const float* v2  = (const float*)d_in[16];
    const float* g1  = (const float*)d_in[17];
    const float* g2  = (const float*)d_in[18];
    const float* k_k = (const float*)d_in[19];
    const float* k_a = (const float*)d_in[20];
    const float* r_k = (const float*)d_in[21];
    const float* Wr  = (const float*)d_in[22];
    const float* Wk  = (const float*)d_in[23];
    const float* Wv  = (const float*)d_in[24];
    const float* Wo  = (const float*)d_in[25];
    const float* lng = (const float*)d_in[26];
    const float* lnb = (const float*)d_in[27];
    float* outp = (float*)d_out;

    float* ws = (float*)d_ws;
    const size_t BIG = (size_t)MROWS * CDIM;   // 4 Mi floats = 16 MB
    float* rbuf  = ws + 0*BIG;
    float* kbuf  = ws + 1*BIG;
    float* vbuf  = ws + 2*BIG;
    float* dbuf  = ws + 3*BIG;   // dec; after pass3: ybf/ghbf live here
    float* kkbuf = ws + 4*BIG;
    float* bbuf  = ws + 5*BIG;
    float* gbuf  = ws + 6*BIG;   // Hbuf during scan
    float* ybuf  = ws + 7*BIG;   // Gbuf during scan
    float* hwbuf = ws + 8*BIG;
    float* vwbuf = hwbuf + (size_t)MROWS*64;
    float* awbuf = vwbuf + (size_t)MROWS*32;
    short* wT    = (short*)(awbuf + (size_t)MROWS*64);
    short* WrT = wT;
    short* WkT = WrT + (size_t)CDIM*CDIM;
    short* WvT = WkT + (size_t)CDIM*CDIM;
    short* WoT = WvT + (size_t)CDIM*CDIM;
    short* g1T = WoT + (size_t)CDIM*CDIM;
    short* g2T = g1T + (size_t)128*CDIM;
    short* w1T = g2T + (size_t)CDIM*128;
    short* v1T = w1T + (size_t)64*CDIM;
    short* a1T = v1T + (size_t)32*CDIM;

    float* Gbuf  = ybuf;
    float* Hbuf  = gbuf;
    float* S0buf = outp;
    short* ybf   = (short*)dbuf;
    short* ghbf  = (short*)dbuf + 4*1024*1024;

    const dim3 blk(256);

    transpose_cvt<<<dim3(CDIM/32, CDIM/32), blk, 0, stream>>>(Wr, WrT, CDIM, CDIM);
    transpose_cvt<<<dim3(CDIM/32, CDIM/32), blk, 0, stream>>>(Wk, WkT, CDIM, CDIM);
    transpose_cvt<<<dim3(CDIM/32, CDIM/32), blk, 0, stream>>>(Wv, WvT, CDIM, CDIM);
    transpose_cvt<<<dim3(CDIM/32, CDIM/32), blk, 0, stream>>>(Wo, WoT, CDIM, CDIM);
    transpose_cvt<<<dim3(128/32,  CDIM/32), blk, 0, stream>>>(g1, g1T, CDIM, 128);
    transpose_cvt<<<dim3(CDIM/32, 128/32),  blk, 0, stream>>>(g2, g2T, 128, CDIM);
    transpose_cvt<<<dim3(64/32,   CDIM/32), blk, 0, stream>>>(w1, w1T, CDIM, 64);
    transpose_cvt<<<dim3(32/32,   CDIM/32), blk, 0, stream>>>(v1, v1T, CDIM, 32);
    transpose_cvt<<<dim3(64/32,   CDIM/32), blk, 0, stream>>>(a1, a1T, CDIM, 64);

    const dim3 gBig(CDIM/128, MROWS/128);
    const dim3 gOne(1, MROWS/128);

    gemm_mfma<128,0,true,false><<<gBig, blk, 0, stream>>>(x, WrT, rbuf, MROWS, CDIM, CDIM, x_r);
    gemm_mfma<128,0,true,false><<<gBig, blk, 0, stream>>>(x, WkT, kbuf, MROWS, CDIM, CDIM, x_k);
    gemm_mfma<128,0,true,false><<<gBig, blk, 0, stream>>>(x, WvT, vbuf, MROWS, CDIM, CDIM, x_v);
    gemm_mfma< 64,1,true,false><<<gOne, blk, 0, stream>>>(x, w1T, hwbuf, MROWS,  64, CDIM, x_w);
    gemm_mfma< 32,0,true,false><<<gOne, blk, 0, stream>>>(x, v1T, vwbuf, MROWS,  32, CDIM, x_v);
    gemm_mfma< 64,0,true,false><<<gOne, blk, 0, stream>>>(x, a1T, awbuf, MROWS,  64, CDIM, x_a);

    post_kernel<<<dim3(MROWS), dim3(1024), 0, stream>>>(
        hwbuf, vwbuf, awbuf, w2, v2, a2, w0, v0p, a0, k_k, k_a, vfirst,
        kbuf, vbuf, dbuf, kkbuf, bbuf);

    scan_pass1<<<dim3(NCHUNK, NBH), dim3(128), 0, stream>>>(
        dbuf, kbuf, vbuf, kkbuf, bbuf, Gbuf, Hbuf);
    scan_pass2<<<dim3(4, NBH), dim3(256), 0, stream>>>(Gbuf, Hbuf, S0buf);
    scan_pass3_mfma<<<dim3(NCHUNK, NBH), dim3(64), 0, stream>>>(
        rbuf, dbuf, kbuf, vbuf, kkbuf, bbuf, S0buf, ybuf);

    gemm_mfma<128,2,true,true ><<<gOne, blk, 0, stream>>>(x, g1T, ghbf, MROWS, 128, CDIM, x_g);
    gemm_mfma<128,0,false,false><<<gBig, blk, 0, stream>>>(ghbf, g2T, gbuf, MROWS, CDIM, 128, nullptr);

    gn_kernel<<<dim3(MROWS), dim3(1024), 0, stream>>>(
        rbuf, kbuf, vbuf, gbuf, r_k, lng, lnb, ybuf, ybf);

    gemm_mfma<128,0,false,false><<<gBig, blk, 0, stream>>>(ybf, WoT, outp, MROWS, CDIM, CDIM, nullptr);
}

// Round 6
// 698.142 us; speedup vs baseline: 8.8450x; 1.0868x over previous
//
#include <hip/hip_runtime.h>
#include <hip/hip_bf16.h>
#include <math.h>

#define TSEQ 2048
#define HEADS 16
#define HSZ 64
#define CDIM 1024
#define MROWS 4096   // B*T
#define CHUNK 64
#define NCHUNK (TSEQ/CHUNK)   // 32
#define NBH 32                // B*HEADS
#define LSTR 68               // LDS row stride (shorts) for 64-wide bf16 mats

typedef short bf16x8 __attribute__((ext_vector_type(8)));
typedef short bf16x4 __attribute__((ext_vector_type(4)));
typedef float f32x4 __attribute__((ext_vector_type(4)));

__device__ __forceinline__ float sigf(float x) { return 1.0f / (1.0f + expf(-x)); }

__device__ __forceinline__ short to_bf16(float f) {
    __hip_bfloat16 h = __float2bfloat16(f);
    return *reinterpret_cast<short*>(&h);
}

// ---------------------------------------------------------------------------
// Weight transpose + f32->bf16 convert:  W [K,N] f32  ->  Wt [N,K] bf16
// ---------------------------------------------------------------------------
__global__ __launch_bounds__(256)
void transpose_cvt(const float* __restrict__ W, short* __restrict__ Wt,
                   const int K, const int N)
{
    __shared__ float t[32][33];
    const int k0 = blockIdx.y * 32, n0 = blockIdx.x * 32;
    const int lx = threadIdx.x & 31, ly = threadIdx.x >> 5;   // ly 0..7
#pragma unroll
    for (int i = 0; i < 4; ++i)
        t[ly + i*8][lx] = W[(size_t)(k0 + ly + i*8)*N + n0 + lx];
    __syncthreads();
#pragma unroll
    for (int i = 0; i < 4; ++i)
        Wt[(size_t)(n0 + ly + i*8)*K + k0 + lx] = to_bf16(t[lx][ly + i*8]);
}

// ---------------------------------------------------------------------------
// bf16 MFMA GEMM:  C[M,N] = act( A'[M,K] @ Bt[N,K]^T )   (round-4, verified)
// ---------------------------------------------------------------------------
template<int BN, int ACT, bool MIX, bool OBF16>
__global__ __launch_bounds__(256)
void gemm_mfma(const void* __restrict__ Aptr, const short* __restrict__ Bt,
               void* __restrict__ Cptr, const int M, const int N, const int K,
               const float* __restrict__ mixv)
{
    constexpr int BM = 128, BK = 32;
    constexpr int ASTR = BK + 8;
    constexpr int NWC = (BN >= 128) ? 2 : 1;
    constexpr int NWR = 4 / NWC;
    constexpr int WM = BM / NWR;
    constexpr int WN = BN / NWC;
    constexpr int AM = WM / 16;
    constexpr int AN = WN / 16;

    __shared__ short As[BM * ASTR];
    __shared__ short Bs[BN * ASTR];

    const int tid  = threadIdx.x;
    const int bm   = blockIdx.y * BM;
    const int bn   = blockIdx.x * BN;
    const int wid  = tid >> 6;
    const int lane = tid & 63;
    const int wr   = wid / NWC;
    const int wc   = wid % NWC;
    const int lrow = lane & 15;
    const int koff = (lane >> 4) * 8;

    f32x4 acc[AM][AN];
#pragma unroll
    for (int m = 0; m < AM; ++m)
#pragma unroll
        for (int n = 0; n < AN; ++n)
            acc[m][n] = (f32x4){0.f, 0.f, 0.f, 0.f};

    for (int k0 = 0; k0 < K; k0 += BK) {
        __syncthreads();
        if (MIX) {
            const float* A = (const float*)Aptr;
#pragma unroll
            for (int p = 0; p < (BM*BK)/(256*4); ++p) {
                const int flat = p*1024 + tid*4;
                const int row = flat >> 5;
                const int kc  = flat & 31;
                const int m   = bm + row;
                const float* xp = A + (size_t)m*K + k0 + kc;
                float4 xv = *(const float4*)xp;
                float4 xs = make_float4(0.f, 0.f, 0.f, 0.f);
                if ((m & (TSEQ-1)) != 0) xs = *(const float4*)(xp - K);
                const float4 mv = *(const float4*)(mixv + k0 + kc);
                xv.x += (xs.x - xv.x) * mv.x;
                xv.y += (xs.y - xv.y) * mv.y;
                xv.z += (xs.z - xv.z) * mv.z;
                xv.w += (xs.w - xv.w) * mv.w;
                bf16x4 o;
                o[0] = to_bf16(xv.x); o[1] = to_bf16(xv.y);
                o[2] = to_bf16(xv.z); o[3] = to_bf16(xv.w);
                *(bf16x4*)&As[row*ASTR + kc] = o;
            }
        } else {
            const short* A = (const short*)Aptr;
#pragma unroll
            for (int p = 0; p < (BM*BK)/(256*8); ++p) {
                const int c = p*256 + tid;
                const int row = c >> 2;
                const int kc  = (c & 3) * 8;
                *(bf16x8*)&As[row*ASTR + kc] =
                    *(const bf16x8*)(A + (size_t)(bm+row)*K + k0 + kc);
            }
        }
        {
            constexpr int CHUNKS = (BN*BK)/8;
#pragma unroll
            for (int p = 0; p < (CHUNKS + 255)/256; ++p) {
                const int c = p*256 + tid;
                if ((CHUNKS & 255) == 0 || c < CHUNKS) {
                    const int col = c >> 2;
                    const int kc  = (c & 3) * 8;
                    *(bf16x8*)&Bs[col*ASTR + kc] =
                        *(const bf16x8*)(Bt + (size_t)(bn+col)*K + k0 + kc);
                }
            }
        }
        __syncthreads();

        bf16x8 af[AM], bfv[AN];
#pragma unroll
        for (int m = 0; m < AM; ++m)
            af[m] = *(const bf16x8*)&As[(wr*WM + m*16 + lrow)*ASTR + koff];
#pragma unroll
        for (int n = 0; n < AN; ++n)
            bfv[n] = *(const bf16x8*)&Bs[(wc*WN + n*16 + lrow)*ASTR + koff];
#pragma unroll
        for (int m = 0; m < AM; ++m)
#pragma unroll
            for (int n = 0; n < AN; ++n)
                acc[m][n] = __builtin_amdgcn_mfma_f32_16x16x32_bf16(
                    af[m], bfv[n], acc[m][n], 0, 0, 0);
    }

    const int r0 = (lane >> 4) * 4;
#pragma unroll
    for (int m = 0; m < AM; ++m) {
#pragma unroll
        for (int n = 0; n < AN; ++n) {
#pragma unroll
            for (int j = 0; j < 4; ++j) {
                const int row = bm + wr*WM + m*16 + r0 + j;
                const int col = bn + wc*WN + n*16 + lrow;
                float vv = acc[m][n][j];
                if (ACT == 1) vv = tanhf(vv);
                else if (ACT == 2) vv = sigf(vv);
                if (OBF16) ((short*)Cptr)[(size_t)row*N + col] = to_bf16(vv);
                else       ((float*)Cptr)[(size_t)row*N + col] = vv;
            }
        }
    }
}

// ---------------------------------------------------------------------------
// Per-row post-processing, pure elementwise now (low-rank 2nd-stage GEMMs
// moved to MFMA). 256 threads/row, float4 per lane; l2norm reduce over
// 16-lane head groups.
// ---------------------------------------------------------------------------
__global__ __launch_bounds__(256)
void post_kernel(const float* __restrict__ tw, const float* __restrict__ vv,
                 const float* __restrict__ aa,
                 const float* __restrict__ w0, const float* __restrict__ v0p,
                 const float* __restrict__ a0p,
                 const float* __restrict__ k_k, const float* __restrict__ k_a,
                 const float* __restrict__ vfirst,
                 float* __restrict__ kio, float* __restrict__ vio,
                 float* __restrict__ dout, float* __restrict__ kkout,
                 float* __restrict__ bout)
{
    const int m  = blockIdx.x;
    const int c4 = threadIdx.x;              // channel quad 0..255
    const size_t o4 = (size_t)m*256 + c4;
    const int cc = c4*4;

    const float4 twv = ((const float4*)tw)[o4];
    const float4 vvv = ((const float4*)vv)[o4];
    const float4 aav = ((const float4*)aa)[o4];
    const float4 kv  = ((const float4*)kio)[o4];
    const float4 vv0 = ((const float4*)vio)[o4];
    const float4 vfv = ((const float4*)vfirst)[o4];
    const float4 w0v = *(const float4*)(w0 + cc);
    const float4 v0v = *(const float4*)(v0p + cc);
    const float4 a0v = *(const float4*)(a0p + cc);
    const float4 kkc = *(const float4*)(k_k + cc);
    const float4 kac = *(const float4*)(k_a + cc);

    float dec[4], vnew[4], av[4], kkr[4], knew[4];
    const float tws[4] = {twv.x, twv.y, twv.z, twv.w};
    const float vvs[4] = {vvv.x, vvv.y, vvv.z, vvv.w};
    const float aas[4] = {aav.x, aav.y, aav.z, aav.w};
    const float ks[4]  = {kv.x, kv.y, kv.z, kv.w};
    const float vs[4]  = {vv0.x, vv0.y, vv0.z, vv0.w};
    const float vfs[4] = {vfv.x, vfv.y, vfv.z, vfv.w};
    const float w0s[4] = {w0v.x, w0v.y, w0v.z, w0v.w};
    const float v0s[4] = {v0v.x, v0v.y, v0v.z, v0v.w};
    const float a0s[4] = {a0v.x, a0v.y, a0v.z, a0v.w};
    const float kks[4] = {kkc.x, kkc.y, kkc.z, kkc.w};
    const float kas[4] = {kac.x, kac.y, kac.z, kac.w};

    float ss = 0.f;
#pragma unroll
    for (int i = 0; i < 4; ++i) {
        dec[i]  = expf(-0.6065306597126334f * sigf(w0s[i] + tws[i]));
        const float sv = sigf(v0s[i] + vvs[i]);
        vnew[i] = vs[i] + (vfs[i] - vs[i]) * sv;
        av[i]   = sigf(a0s[i] + aas[i]);
        kkr[i]  = ks[i] * kks[i];
        knew[i] = ks[i] * (1.f + (av[i] - 1.f) * kas[i]);
        ss = fmaf(kkr[i], kkr[i], ss);
    }
    // head = 16 consecutive lanes (64 channels); xor masks 1,2,4,8
#pragma unroll
    for (int mask = 1; mask < 16; mask <<= 1) ss += __shfl_xor(ss, mask);
    const float inv = fmaxf(rsqrtf(ss + 1e-12f), 1e-12f);

    float4 decv, vnv, knv, kkv4, bv4;
    decv.x = dec[0]; decv.y = dec[1]; decv.z = dec[2]; decv.w = dec[3];
    vnv.x = vnew[0]; vnv.y = vnew[1]; vnv.z = vnew[2]; vnv.w = vnew[3];
    knv.x = knew[0]; knv.y = knew[1]; knv.z = knew[2]; knv.w = knew[3];
    kkv4.x = kkr[0]*inv; kkv4.y = kkr[1]*inv; kkv4.z = kkr[2]*inv; kkv4.w = kkr[3]*inv;
    bv4.x = kkv4.x*av[0]; bv4.y = kkv4.y*av[1]; bv4.z = kkv4.z*av[2]; bv4.w = kkv4.w*av[3];

    ((float4*)dout)[o4]  = decv;
    ((float4*)vio)[o4]   = vnv;
    ((float4*)kio)[o4]   = knv;
    ((float4*)kkout)[o4] = kkv4;
    ((float4*)bout)[o4]  = bv4;
}

// ---------------------------------------------------------------------------
// Scan pass 1 (scalar, unchanged): chunk transition G and offset H.
// ---------------------------------------------------------------------------
__global__ __launch_bounds__(128)
void scan_pass1(const float* __restrict__ d, const float* __restrict__ k,
                const float* __restrict__ v, const float* __restrict__ kk,
                const float* __restrict__ bb,
                float* __restrict__ Gbuf, float* __restrict__ Hbuf)
{
    const int chunk = blockIdx.x;
    const int bh = blockIdx.y;
    const int b = bh >> 4, h = bh & 15;
    const int tid = threadIdx.x;
    const int lane = tid & 63;
    const int isH = tid >> 6;

    __shared__ float sv[4][64];   // 0=kk 1=d 2=bb 3=k

    float row[HSZ];
#pragma unroll
    for (int j = 0; j < HSZ; ++j)
        row[j] = (!isH && j == lane) ? 1.f : 0.f;

    size_t off = ((size_t)b*TSEQ + (size_t)chunk*CHUNK) * CDIM + h*HSZ;
    for (int t = 0; t < CHUNK; ++t, off += CDIM) {
        const float vi = isH ? v[off + lane] : 0.f;
        __syncthreads();
        if (!isH) { sv[0][lane] = kk[off + lane]; sv[2][lane] = bb[off + lane]; }
        else      { sv[1][lane] = d[off + lane];  sv[3][lane] = k[off + lane]; }
        __syncthreads();

        float g0 = 0.f, g1 = 0.f, g2 = 0.f, g3 = 0.f;
#pragma unroll
        for (int j4 = 0; j4 < 16; ++j4) {
            const float4 kv = *(const float4*)&sv[0][j4*4];
            g0 = fmaf(row[j4*4+0], kv.x, g0);
            g1 = fmaf(row[j4*4+1], kv.y, g1);
            g2 = fmaf(row[j4*4+2], kv.z, g2);
            g3 = fmaf(row[j4*4+3], kv.w, g3);
        }
        const float ga = -((g0 + g1) + (g2 + g3));

        if (isH) {
#pragma unroll
            for (int j4 = 0; j4 < 16; ++j4) {
                const float4 dv = *(const float4*)&sv[1][j4*4];
                const float4 bv = *(const float4*)&sv[2][j4*4];
                const float4 kv = *(const float4*)&sv[3][j4*4];
                row[j4*4+0] = fmaf(row[j4*4+0], dv.x, fmaf(ga, bv.x, vi * kv.x));
                row[j4*4+1] = fmaf(row[j4*4+1], dv.y, fmaf(ga, bv.y, vi * kv.y));
                row[j4*4+2] = fmaf(row[j4*4+2], dv.z, fmaf(ga, bv.z, vi * kv.z));
                row[j4*4+3] = fmaf(row[j4*4+3], dv.w, fmaf(ga, bv.w, vi * kv.w));
            }
        } else {
#pragma unroll
            for (int j4 = 0; j4 < 16; ++j4) {
                const float4 dv = *(const float4*)&sv[1][j4*4];
                const float4 bv = *(const float4*)&sv[2][j4*4];
                row[j4*4+0] = fmaf(row[j4*4+0], dv.x, ga * bv.x);
                row[j4*4+1] = fmaf(row[j4*4+1], dv.y, ga * bv.y);
                row[j4*4+2] = fmaf(row[j4*4+2], dv.z, ga * bv.z);
                row[j4*4+3] = fmaf(row[j4*4+3], dv.w, ga * bv.w);
            }
        }
    }

    float* dst = (isH ? Hbuf : Gbuf) + (((size_t)bh*NCHUNK + chunk)*HSZ + lane)*HSZ;
#pragma unroll
    for (int j4 = 0; j4 < 16; ++j4)
        *(float4*)&dst[j4*4] = make_float4(row[j4*4+0], row[j4*4+1], row[j4*4+2], row[j4*4+3]);
}

// ---------------------------------------------------------------------------
// Scan pass 2 (unchanged): propagate chunk-boundary states.
// ---------------------------------------------------------------------------
__global__ __launch_bounds__(256)
void scan_pass2(const float* __restrict__ Gbuf, const float* __restrict__ Hbuf,
                float* __restrict__ S0buf)
{
    const int rg = blockIdx.x;
    const int bh = blockIdx.y;
    const int tid = threadIdx.x;
    const int il = tid & 15;
    const int q4 = tid >> 4;
    const int row = rg*16 + il;

    __shared__ float Gs[64][68];
    __shared__ float Ssh[16][68];

    float frag[4] = {0.f, 0.f, 0.f, 0.f};
    *(float4*)&Ssh[il][q4*4] = make_float4(0.f, 0.f, 0.f, 0.f);

    for (int c = 0; c < NCHUNK; ++c) {
        const size_t mbase = ((size_t)bh*NCHUNK + c)*HSZ*HSZ;
#pragma unroll
        for (int p = 0; p < 4; ++p) {
            const int f = tid*16 + p*4;
            const int rr = f >> 6, cc = f & 63;
            *(float4*)&Gs[rr][cc] = *(const float4*)(Gbuf + mbase + f);
        }
        *(float4*)(S0buf + mbase + (size_t)row*HSZ + q4*4) =
            make_float4(frag[0], frag[1], frag[2], frag[3]);
        __syncthreads();

        float4 hv = *(const float4*)(Hbuf + mbase + (size_t)row*HSZ + q4*4);
        float a0 = hv.x, a1 = hv.y, a2 = hv.z, a3 = hv.w;
#pragma unroll
        for (int j = 0; j < 64; ++j) {
            const float sj = Ssh[il][j];
            const float4 gv = *(const float4*)&Gs[j][q4*4];
            a0 = fmaf(sj, gv.x, a0);
            a1 = fmaf(sj, gv.y, a1);
            a2 = fmaf(sj, gv.z, a2);
            a3 = fmaf(sj, gv.w, a3);
        }
        __syncthreads();
        frag[0] = a0; frag[1] = a1; frag[2] = a2; frag[3] = a3;
        *(float4*)&Ssh[il][q4*4] = make_float4(a0, a1, a2, a3);
    }
}

// ---------------------------------------------------------------------------
// Pass-3 MFMA helpers (round-5, verified)
// ---------------------------------------------------------------------------
__device__ __forceinline__ void zero44(f32x4 a[4][4]) {
#pragma unroll
    for (int m = 0; m < 4; ++m)
#pragma unroll
        for (int n = 0; n < 4; ++n) a[m][n] = (f32x4){0.f, 0.f, 0.f, 0.f};
}

__device__ __forceinline__ void mm_nt_lds(const short* __restrict__ Ab,
                                          const short* __restrict__ Bb,
                                          f32x4 acc[4][4], const int lane)
{
    const int lrow = lane & 15;
    const int ko   = (lane >> 4) * 8;
#pragma unroll
    for (int kh = 0; kh < 2; ++kh) {
        bf16x8 af[4], bfv[4];
#pragma unroll
        for (int m = 0; m < 4; ++m)
            af[m] = *(const bf16x8*)&Ab[(m*16 + lrow)*LSTR + kh*32 + ko];
#pragma unroll
        for (int n = 0; n < 4; ++n)
            bfv[n] = *(const bf16x8*)&Bb[(n*16 + lrow)*LSTR + kh*32 + ko];
#pragma unroll
        for (int m = 0; m < 4; ++m)
#pragma unroll
            for (int n = 0; n < 4; ++n)
                acc[m][n] = __builtin_amdgcn_mfma_f32_16x16x32_bf16(
                    af[m], bfv[n], acc[m][n], 0, 0, 0);
    }
}

__device__ __forceinline__ void mm_nt_gf32(const short* __restrict__ Ab,
                                           const float* __restrict__ Bg,
                                           f32x4 acc[4][4], const int lane)
{
    const int lrow = lane & 15;
    const int ko   = (lane >> 4) * 8;
#pragma unroll
    for (int kh = 0; kh < 2; ++kh) {
        bf16x8 af[4], bfv[4];
#pragma unroll
        for (int m = 0; m < 4; ++m)
            af[m] = *(const bf16x8*)&Ab[(m*16 + lrow)*LSTR + kh*32 + ko];
#pragma unroll
        for (int n = 0; n < 4; ++n) {
            const float* p = Bg + (size_t)(n*16 + lrow)*64 + kh*32 + ko;
            const float4 u0 = *(const float4*)p;
            const float4 u1 = *(const float4*)(p + 4);
            bf16x8 bv;
            bv[0] = to_bf16(u0.x); bv[1] = to_bf16(u0.y);
            bv[2] = to_bf16(u0.z); bv[3] = to_bf16(u0.w);
            bv[4] = to_bf16(u1.x); bv[5] = to_bf16(u1.y);
            bv[6] = to_bf16(u1.z); bv[7] = to_bf16(u1.w);
            bfv[n] = bv;
        }
#pragma unroll
        for (int m = 0; m < 4; ++m)
#pragma unroll
            for (int n = 0; n < 4; ++n)
                acc[m][n] = __builtin_amdgcn_mfma_f32_16x16x32_bf16(
                    af[m], bfv[n], acc[m][n], 0, 0, 0);
    }
}

template<int MASK, bool WRN, bool WRT>
__device__ __forceinline__ void acc_store(const f32x4 acc[4][4],
                                          short* __restrict__ dst,
                                          short* __restrict__ dstT,
                                          const int lane)
{
    const int r0 = (lane >> 4) * 4;
    const int c0 = lane & 15;
#pragma unroll
    for (int m = 0; m < 4; ++m)
#pragma unroll
        for (int n = 0; n < 4; ++n)
#pragma unroll
            for (int j = 0; j < 4; ++j) {
                const int row = m*16 + r0 + j;
                const int col = n*16 + c0;
                float vv = acc[m][n][j];
                if (MASK == 1 && col >= row) vv = 0.f;
                if (MASK == 2 && col >  row) vv = 0.f;
                const short bv = to_bf16(vv);
                if (WRN) dst [row*LSTR + col] = bv;
                if (WRT) dstT[col*LSTR + row] = bv;
            }
}

// ---------------------------------------------------------------------------
// Scan pass 3, MFMA chunk form (round-5, verified).
// ---------------------------------------------------------------------------
__global__ __launch_bounds__(64)
void scan_pass3_mfma(const float* __restrict__ r, const float* __restrict__ d,
                     const float* __restrict__ k, const float* __restrict__ v,
                     const float* __restrict__ kk, const float* __restrict__ bb,
                     const float* __restrict__ S0buf, float* __restrict__ y)
{
    __shared__ short Ah[64*LSTR], Bh[64*LSTR], Kh[64*LSTR], Rh[64*LSTR];
    __shared__ short Vt[64*LSTR], Cb[64*LSTR], Nb[64*LSTR], Nt[64*LSTR], Xt[64*LSTR];

    const int chunk = blockIdx.x;
    const int bh = blockIdx.y;
    const int b = bh >> 4, h = bh & 15;
    const int lane = threadIdx.x;

    size_t off = ((size_t)b*TSEQ + (size_t)chunk*CHUNK)*CDIM + h*HSZ + lane;
    float run = 0.f;
    for (int t = 0; t < CHUNK; ++t, off += CDIM) {
        const float de    = d[off];
        const float cprev = run;
        run += logf(de);
        Ah[t*LSTR + lane] = to_bf16(-kk[off] * expf(cprev));
        Bh[t*LSTR + lane] = to_bf16(bb[off] * expf(-run));
        Kh[t*LSTR + lane] = to_bf16(k[off]  * expf(-run));
        Rh[t*LSTR + lane] = to_bf16(r[off]  * expf(run));
        Vt[lane*LSTR + t] = to_bf16(v[off]);
    }
    __syncthreads();

    const float* S0g = S0buf + ((size_t)bh*NCHUNK + chunk)*HSZ*HSZ;

    f32x4 acc[4][4], xacc[4][4];

    zero44(acc);  mm_nt_lds(Ah, Bh, acc, lane);
    acc_store<1, true, true>(acc, Nb, Nt, lane);
    zero44(acc);  mm_nt_lds(Ah, Kh, acc, lane);
    acc_store<1, true, false>(acc, Cb, nullptr, lane);
    __syncthreads();

    zero44(xacc);
    mm_nt_gf32(Ah, S0g, xacc, lane);
    mm_nt_lds(Cb, Vt, xacc, lane);
    acc_store<0, false, true>(xacc, nullptr, Xt, lane);
    __syncthreads();

#pragma unroll 1
    for (int rd = 0; rd < 6; ++rd) {
        mm_nt_lds(Nb, Xt, xacc, lane);
        if (rd < 5) { zero44(acc); mm_nt_lds(Nb, Nt, acc, lane); }
        __syncthreads();
        acc_store<0, false, true>(xacc, nullptr, Xt, lane);
        if (rd < 5) acc_store<0, true, true>(acc, Nb, Nt, lane);
        __syncthreads();
    }

    zero44(acc);  mm_nt_lds(Rh, Bh, acc, lane);
    acc_store<2, true, false>(acc, Cb, nullptr, lane);
    zero44(acc);  mm_nt_lds(Rh, Kh, acc, lane);
    acc_store<2, true, false>(acc, Nb, nullptr, lane);
    __syncthreads();

    zero44(acc);
    mm_nt_gf32(Rh, S0g, acc, lane);
    mm_nt_lds(Cb, Xt, acc, lane);
    mm_nt_lds(Nb, Vt, acc, lane);

    const int r0 = (lane >> 4) * 4;
    const int c0 = lane & 15;
    float* yb = y + ((size_t)b*TSEQ + (size_t)chunk*CHUNK)*CDIM + h*HSZ;
#pragma unroll
    for (int m = 0; m < 4; ++m)
#pragma unroll
        for (int n = 0; n < 4; ++n)
#pragma unroll
            for (int j = 0; j < 4; ++j)
                yb[(size_t)(m*16 + r0 + j)*CDIM + n*16 + c0] = acc[m][n][j];
}

// ---------------------------------------------------------------------------
// GroupNorm + rank-1 rwkv residual + *g; writes bf16 (y*g) for the Wo GEMM.
// ---------------------------------------------------------------------------
__global__ __launch_bounds__(1024)
void gn_kernel(const float* __restrict__ r, const float* __restrict__ k,
               const float* __restrict__ v, const float* __restrict__ g,
               const float* __restrict__ rk, const float* __restrict__ gamma,
               const float* __restrict__ beta, const float* __restrict__ y,
               short* __restrict__ ybf)
{
    const int m = blockIdx.x;
    const int c = threadIdx.x;
    const size_t o = (size_t)m*CDIM + c;
    const float yv = y[o];
    float s1 = yv, s2 = yv*yv;
#pragma unroll
    for (int mask = 1; mask < 64; mask <<= 1) {
        s1 += __shfl_xor(s1, mask);
        s2 += __shfl_xor(s2, mask);
    }
    const float mu  = s1 * (1.f/HSZ);
    const float var = s2 * (1.f/HSZ) - mu*mu;
    const float gn  = (yv - mu) * rsqrtf(var + 0.00064f) * gamma[c] + beta[c];

    float p = r[o] * k[o] * rk[c];
#pragma unroll
    for (int mask = 1; mask < 64; mask <<= 1) p += __shfl_xor(p, mask);

    ybf[o] = to_bf16((gn + p * v[o]) * g[o]);
}

// ---------------------------------------------------------------------------
extern "C" void kernel_launch(void* const* d_in, const int* in_sizes, int n_in,
                              void* d_out, int out_size, void* d_ws, size_t ws_size,
                              hipStream_t stream)
{
    const float* x      = (const float*)d_in[0];
    const float* vfirst = (const float*)d_in[1];
    const float* x_r = (const float*)d_in[2];
    const float* x_w = (const float*)d_in[3];
    const float* x_k = (const float*)d_in[4];
    const float* x_v = (const float*)d_in[5];
    const float* x_a = (const float*)d_in[6];
    const float* x_g = (const float*)d_in[7];
    const float* w0  = (const float*)d_in[8];
    const float* w1  = (const float*)d_in[9];
    const float* w2  = (const float*)d_in[10];
    const float* a0  = (const float*)d_in[11];
    const float* a1  = (const float*)d_in[12];
    const float* a2  = (const float*)d_in[13];
    const float* v0p = (const float*)d_in[14];
    const float* v1  = (const float*)d_in[15];
    const float* v2  = (const float*)d_in[16];
    const float* g1  = (const float*)d_in[17];
    const float* g2  = (const float*)d_in[18];
    const float* k_k = (const float*)d_in[19];
    const float* k_a = (const float*)d_in[20];
    const float* r_k = (const float*)d_in[21];
    const float* Wr  = (const float*)d_in[22];
    const float* Wk  = (const float*)d_in[23];
    const float* Wv  = (const float*)d_in[24];
    const float* Wo  = (const float*)d_in[25];
    const float* lng = (const float*)d_in[26];
    const float* lnb = (const float*)d_in[27];
    float* outp = (float*)d_out;

    float* ws = (float*)d_ws;
    const size_t BIG = (size_t)MROWS * CDIM;   // 4 Mi floats = 16 MB
    float* rbuf  = ws + 0*BIG;
    float* kbuf  = ws + 1*BIG;
    float* vbuf  = ws + 2*BIG;
    float* dbuf  = ws + 3*BIG;   // dec; after pass3: ybf/ghbf live here
    float* kkbuf = ws + 4*BIG;
    float* bbuf  = ws + 5*BIG;
    float* gbuf  = ws + 6*BIG;   // vvbuf before post; Hbuf during scan; g after
    float* ybuf  = ws + 7*BIG;   // twbuf before post; Gbuf during scan; y after
    float* hwbuf = ws + 8*BIG;
    float* vwbuf = hwbuf + (size_t)MROWS*64;
    float* awbuf = vwbuf + (size_t)MROWS*32;
    short* wT    = (short*)(awbuf + (size_t)MROWS*64);
    short* WrT = wT;
    short* WkT = WrT + (size_t)CDIM*CDIM;
    short* WvT = WkT + (size_t)CDIM*CDIM;
    short* WoT = WvT + (size_t)CDIM*CDIM;
    short* g1T = WoT + (size_t)CDIM*CDIM;
    short* g2T = g1T + (size_t)128*CDIM;
    short* w1T = g2T + (size_t)CDIM*128;
    short* v1T = w1T + (size_t)64*CDIM;
    short* a1T = v1T + (size_t)32*CDIM;
    short* w2T = a1T + (size_t)64*CDIM;       // [1024][64]
    short* v2T = w2T + (size_t)CDIM*64;       // [1024][32]
    short* a2T = v2T + (size_t)CDIM*32;       // [1024][64]

    // bf16 first-stage outputs (reuse the hw/vw/aw small region)
    short* hwbf = (short*)hwbuf;              // [4096][64]
    short* vwbf = hwbf + (size_t)MROWS*64;    // [4096][32]
    short* awbf = vwbf + (size_t)MROWS*32;    // [4096][64]

    // second-stage f32 outputs aliased onto dead BIG regions
    float* twbuf = ybuf;                      // free until pass1 (Gbuf)
    float* vvbuf = gbuf;                      // free until pass1 (Hbuf)
    float* aabuf = outp;                      // free until pass2 (S0buf)

    float* Gbuf  = ybuf;
    float* Hbuf  = gbuf;
    float* S0buf = outp;
    short* ybf   = (short*)dbuf;
    short* ghbf  = (short*)dbuf + 4*1024*1024;

    const dim3 blk(256);

    transpose_cvt<<<dim3(CDIM/32, CDIM/32), blk, 0, stream>>>(Wr, WrT, CDIM, CDIM);
    transpose_cvt<<<dim3(CDIM/32, CDIM/32), blk, 0, stream>>>(Wk, WkT, CDIM, CDIM);
    transpose_cvt<<<dim3(CDIM/32, CDIM/32), blk, 0, stream>>>(Wv, WvT, CDIM, CDIM);
    transpose_cvt<<<dim3(CDIM/32, CDIM/32), blk, 0, stream>>>(Wo, WoT, CDIM, CDIM);
    transpose_cvt<<<dim3(128/32,  CDIM/32), blk, 0, stream>>>(g1, g1T, CDIM, 128);
    transpose_cvt<<<dim3(CDIM/32, 128/32),  blk, 0, stream>>>(g2, g2T, 128, CDIM);
    transpose_cvt<<<dim3(64/32,   CDIM/32), blk, 0, stream>>>(w1, w1T, CDIM, 64);
    transpose_cvt<<<dim3(32/32,   CDIM/32), blk, 0, stream>>>(v1, v1T, CDIM, 32);
    transpose_cvt<<<dim3(64/32,   CDIM/32), blk, 0, stream>>>(a1, a1T, CDIM, 64);
    transpose_cvt<<<dim3(CDIM/32, 64/32),   blk, 0, stream>>>(w2, w2T, 64, CDIM);
    transpose_cvt<<<dim3(CDIM/32, 32/32),   blk, 0, stream>>>(v2, v2T, 32, CDIM);
    transpose_cvt<<<dim3(CDIM/32, 64/32),   blk, 0, stream>>>(a2, a2T, 64, CDIM);

    const dim3 gBig(CDIM/128, MROWS/128);
    const dim3 gOne(1, MROWS/128);

    // big projections (mix fused into A-staging)
    gemm_mfma<128,0,true,false><<<gBig, blk, 0, stream>>>(x, WrT, rbuf, MROWS, CDIM, CDIM, x_r);
    gemm_mfma<128,0,true,false><<<gBig, blk, 0, stream>>>(x, WkT, kbuf, MROWS, CDIM, CDIM, x_k);
    gemm_mfma<128,0,true,false><<<gBig, blk, 0, stream>>>(x, WvT, vbuf, MROWS, CDIM, CDIM, x_v);
    // low-rank first stages (bf16 out)
    gemm_mfma< 64,1,true,true ><<<gOne, blk, 0, stream>>>(x, w1T, hwbf, MROWS,  64, CDIM, x_w);
    gemm_mfma< 32,0,true,true ><<<gOne, blk, 0, stream>>>(x, v1T, vwbf, MROWS,  32, CDIM, x_v);
    gemm_mfma< 64,0,true,true ><<<gOne, blk, 0, stream>>>(x, a1T, awbf, MROWS,  64, CDIM, x_a);
    // low-rank second stages (MFMA, f32 out)
    gemm_mfma<128,0,false,false><<<gBig, blk, 0, stream>>>(hwbf, w2T, twbuf, MROWS, CDIM, 64, nullptr);
    gemm_mfma<128,0,false,false><<<gBig, blk, 0, stream>>>(vwbf, v2T, vvbuf, MROWS, CDIM, 32, nullptr);
    gemm_mfma<128,0,false,false><<<gBig, blk, 0, stream>>>(awbf, a2T, aabuf, MROWS, CDIM, 64, nullptr);

    post_kernel<<<dim3(MROWS), blk, 0, stream>>>(
        twbuf, vvbuf, aabuf, w0, v0p, a0, k_k, k_a, vfirst,
        kbuf, vbuf, dbuf, kkbuf, bbuf);

    scan_pass1<<<dim3(NCHUNK, NBH), dim3(128), 0, stream>>>(
        dbuf, kbuf, vbuf, kkbuf, bbuf, Gbuf, Hbuf);
    scan_pass2<<<dim3(4, NBH), dim3(256), 0, stream>>>(Gbuf, Hbuf, S0buf);
    scan_pass3_mfma<<<dim3(NCHUNK, NBH), dim3(64), 0, stream>>>(
        rbuf, dbuf, kbuf, vbuf, kkbuf, bbuf, S0buf, ybuf);

    gemm_mfma<128,2,true,true ><<<gOne, blk, 0, stream>>>(x, g1T, ghbf, MROWS, 128, CDIM, x_g);
    gemm_mfma<128,0,false,false><<<gBig, blk, 0, stream>>>(ghbf, g2T, gbuf, MROWS, CDIM, 128, nullptr);

    gn_kernel<<<dim3(MROWS), dim3(1024), 0, stream>>>(
        rbuf, kbuf, vbuf, gbuf, r_k, lng, lnb, ybuf, ybf);

    gemm_mfma<128,0,false,false><<<gBig, blk, 0, stream>>>(ybf, WoT, outp, MROWS, CDIM, CDIM, nullptr);
}